// Round 4
// baseline (458.239 us; speedup 1.0000x reference)
//
#include <hip/hip_runtime.h>
#include <math.h>

#define BB 512
#define NN 128
#define CAND_CAP (512*384)
#define LIMIT 2048

// ---------------- mask decode (int32 / byte / float32 robustness) -------------
__device__ inline bool read_mask(const void* p, int i, int mode){
  if (mode == 0) return ((const int*)p)[i] != 0;
  if (mode == 1) return ((const unsigned char*)p)[i] != 0;
  return ((const float*)p)[i] != 0.0f;
}

__device__ inline float fast_rcp(float x){ return __builtin_amdgcn_rcpf(x); }
__device__ inline float fast_rsq(float x){ return __builtin_amdgcn_rsqf(x); }

__device__ inline void top3_update(float v, float& a1, float& a2, float& a3){
  if (v > a1){ a3=a2; a2=a1; a1=v; }
  else if (v > a2){ a3=a2; a2=v; }
  else if (v > a3){ a3=v; }
}

// ---------------- fp32 Kabsch rotation from 3x3 covariance --------------------
__device__ void kabsch_rot_f(const float H[3][3], float R[3][3]){
  float S[3][3];
  for (int i = 0; i < 3; i++)
    for (int j = 0; j < 3; j++){
      float a = 0.f;
      for (int k = 0; k < 3; k++) a += H[k][i]*H[k][j];
      S[i][j] = a;
    }
  float V[3][3] = {{1,0,0},{0,1,0},{0,0,1}};
  for (int sweep = 0; sweep < 12; sweep++){
    float off  = S[0][1]*S[0][1] + S[0][2]*S[0][2] + S[1][2]*S[1][2];
    float base = S[0][0]*S[0][0] + S[1][1]*S[1][1] + S[2][2]*S[2][2];
    if (off <= base*1e-14f + 1e-36f) break;
    for (int p = 0; p < 2; p++)
      for (int q = p+1; q < 3; q++){
        float apq = S[p][q];
        if (fabsf(apq) <= 1e-30f) continue;
        float tau = (S[q][q] - S[p][p]) * fast_rcp(2.f*apq);
        float tt  = (tau >= 0.f ? 1.f : -1.f) * fast_rcp(fabsf(tau) + sqrtf(1.f + tau*tau));
        float c = fast_rsq(1.f + tt*tt), s = tt*c;
        for (int k = 0; k < 3; k++){ float a=S[k][p], b2=S[k][q]; S[k][p]=c*a-s*b2; S[k][q]=s*a+c*b2; }
        for (int k = 0; k < 3; k++){ float a=S[p][k], b2=S[q][k]; S[p][k]=c*a-s*b2; S[q][k]=s*a+c*b2; }
        for (int k = 0; k < 3; k++){ float a=V[k][p], b2=V[k][q]; V[k][p]=c*a-s*b2; V[k][q]=s*a+c*b2; }
      }
  }
  float lam[3] = { S[0][0], S[1][1], S[2][2] };
  int o0=0,o1=1,o2=2;
  if (lam[o0] < lam[o1]){ int x=o0;o0=o1;o1=x; }
  if (lam[o0] < lam[o2]){ int x=o0;o0=o2;o2=x; }
  if (lam[o1] < lam[o2]){ int x=o1;o1=o2;o2=x; }
  float v0[3]={V[0][o0],V[1][o0],V[2][o0]};
  float v1[3]={V[0][o1],V[1][o1],V[2][o1]};
  float v2[3]={V[0][o2],V[1][o2],V[2][o2]};
  float sig0 = sqrtf(fmaxf(lam[o0], 0.f));
  if (!(sig0 > 1e-12f)){
    for (int i = 0; i < 3; i++) for (int j = 0; j < 3; j++) R[i][j] = (i==j) ? 1.f : 0.f;
    return;
  }
  float u0[3],u1[3],u2[3];
  for (int i = 0; i < 3; i++) u0[i] = H[i][0]*v0[0] + H[i][1]*v0[1] + H[i][2]*v0[2];
  float d0 = u0[0]*u0[0]+u0[1]*u0[1]+u0[2]*u0[2];
  float in0 = fast_rsq(d0);
  for (int i = 0; i < 3; i++) u0[i] *= in0;
  for (int i = 0; i < 3; i++) u1[i] = H[i][0]*v1[0] + H[i][1]*v1[1] + H[i][2]*v1[2];
  float dp = u1[0]*u0[0]+u1[1]*u0[1]+u1[2]*u0[2];
  for (int i = 0; i < 3; i++) u1[i] -= dp*u0[i];
  float d1 = u1[0]*u1[0]+u1[1]*u1[1]+u1[2]*u1[2];
  float n1 = sqrtf(d1);
  if (n1 > sig0*1e-5f){
    float in1 = fast_rsq(d1);
    for (int i = 0; i < 3; i++) u1[i] *= in1;
  } else {
    int k = (fabsf(u0[0])<=fabsf(u0[1]) && fabsf(u0[0])<=fabsf(u0[2])) ? 0 : ((fabsf(u0[1])<=fabsf(u0[2])) ? 1 : 2);
    float e[3] = {0,0,0}; e[k] = 1.f;
    float d2 = e[0]*u0[0]+e[1]*u0[1]+e[2]*u0[2];
    for (int i = 0; i < 3; i++) u1[i] = e[i] - d2*u0[i];
    float nn = fast_rsq(u1[0]*u1[0]+u1[1]*u1[1]+u1[2]*u1[2]);
    for (int i = 0; i < 3; i++) u1[i] *= nn;
  }
  u2[0] = u0[1]*u1[2] - u0[2]*u1[1];
  u2[1] = u0[2]*u1[0] - u0[0]*u1[2];
  u2[2] = u0[0]*u1[1] - u0[1]*u1[0];
  float cx = v1[1]*v2[2] - v1[2]*v2[1];
  float cy = v1[2]*v2[0] - v1[0]*v2[2];
  float cz = v1[0]*v2[1] - v1[1]*v2[0];
  float detV = v0[0]*cx + v0[1]*cy + v0[2]*cz;  // det(U)=+1 by construction
  float dd = (detV >= 0.f) ? 1.f : -1.f;
  for (int i = 0; i < 3; i++)
    for (int j = 0; j < 3; j++)
      R[i][j] = v0[i]*u0[j] + v1[i]*u1[j] + dd*v2[i]*u2[j];
}

// ---------------- K1: raw-score mutual top-3, sparse exp, stats, candidates ---
// 512 threads: thread t -> row r = t&127, quarter q = t>>7 (32 cols/rows each)
__global__ __launch_bounds__(512, 4) void k1_kernel(
    const float* __restrict__ score, const float* __restrict__ refp,
    const float* __restrict__ srcp, const void* __restrict__ rmaskp,
    const void* __restrict__ smaskp, int* hdr, float* cand_vals, int* cand_idx,
    float* Hsr, int* pcount)
{
  __shared__ float tile[NN*NN];        // 64 KB raw-score tile
  __shared__ float part[4][NN][3];     // reused: col partials, then row partials
  __shared__ float c3sh[NN], r3sh[NN];
  __shared__ unsigned char smk[NN], rmk[NN];
  __shared__ float srcsh[NN*3];
  __shared__ float red[8][17];
  __shared__ int wsum[8];
  __shared__ int basesh;
  __shared__ int smode;
  const int b = blockIdx.x, t = threadIdx.x;
  const int r = t & 127, q = t >> 7;
  const int lane = t & 63, wv = t >> 6;

  // mode detect (wave 0): int32 0/1, byte, or float 0/1.0
  if (t < 64){
    unsigned v = ((const unsigned*)rmaskp)[t];
    bool n01 = !(v == 0u || v == 1u);
    bool nf  = !(v == 0u || v == 0x3F800000u);
    unsigned long long b01 = __ballot(n01), bf = __ballot(nf);
    if (t == 0) smode = (b01 == 0ull) ? 0 : ((bf == 0ull) ? 2 : 1);
  }

  // coalesced raw load (no exp!)
  {
    const float4* s4 = (const float4*)(score + (size_t)b*NN*NN);
    float4* t4 = (float4*)tile;
    for (int j = t; j < NN*NN/4; j += 512) t4[j] = s4[j];
  }
  __syncthreads();   // tile + smode ready

  if (t < NN){
    int mode = smode;
    smk[t] = read_mask(smaskp, b*NN + t, mode) ? 1 : 0;
    rmk[t] = read_mask(rmaskp, b*NN + t, mode) ? 1 : 0;
    srcsh[t*3+0] = srcp[(b*NN+t)*3+0];
    srcsh[t*3+1] = srcp[(b*NN+t)*3+1];
    srcsh[t*3+2] = srcp[(b*NN+t)*3+2];
  }
  // column partial top-3: column c=r, rows [q*32, q*32+32)
  {
    float a1=-1e30f, a2=-1e30f, a3=-1e30f;
    for (int i = 0; i < 32; i++){
      float v = tile[(q*32 + i)*NN + r];
      top3_update(v, a1, a2, a3);
    }
    part[q][r][0]=a1; part[q][r][1]=a2; part[q][r][2]=a3;
  }
  __syncthreads();
  if (t < NN){
    float m1=-1e30f, m2=-1e30f, m3=-1e30f;
    for (int qq = 0; qq < 4; qq++)
      for (int j = 0; j < 3; j++) top3_update(part[qq][t][j], m1, m2, m3);
    c3sh[t] = m3;
  }
  __syncthreads();
  // row partial top-3: row r, cols q*32 + ((r+i)&31)  (rotation: 2-way banks, free)
  {
    float a1=-1e30f, a2=-1e30f, a3=-1e30f;
    for (int i = 0; i < 32; i++){
      int c = q*32 + ((r + i) & 31);
      top3_update(tile[r*NN + c], a1, a2, a3);
    }
    part[q][r][0]=a1; part[q][r][1]=a2; part[q][r][2]=a3;
  }
  __syncthreads();
  if (t < NN){
    float m1=-1e30f, m2=-1e30f, m3=-1e30f;
    for (int qq = 0; qq < 4; qq++)
      for (int j = 0; j < 3; j++) top3_update(part[qq][t][j], m1, m2, m3);
    r3sh[t] = m3;
  }
  __syncthreads();

  // masked pass: mutual top-3 on RAW (exp monotone), expf only at survivors
  float wr = 0.f, p0 = 0.f, p1 = 0.f, p2 = 0.f, cntf = 0.f;
  float kv[3]; int km[3]; int cnt = 0;
  const float r3 = r3sh[r];
  const bool rmv = rmk[r] != 0;
  const float rx = refp[(b*NN+r)*3+0], ry = refp[(b*NN+r)*3+1], rz = refp[(b*NN+r)*3+2];
  for (int i = 0; i < 32; i++){
    int c = q*32 + ((r + i) & 31);
    float v = tile[r*NN + c];
    if (rmv && smk[c] && v >= r3 && v >= c3sh[c]){
      float e = expf(v);
      if (e > 0.05f){
        cntf += 1.f; wr += e;
        p0 += e*srcsh[c*3+0]; p1 += e*srcsh[c*3+1]; p2 += e*srcsh[c*3+2];
        if (cnt < 3){ kv[cnt] = e; km[cnt] = c; cnt++; }
      }
    }
  }
  // block-wide exclusive scan of cnt -> single atomic per block
  int x = cnt;
  for (int off2 = 1; off2 < 64; off2 <<= 1){ int y = __shfl_up(x, off2); if (lane >= off2) x += y; }
  if (lane == 63) wsum[wv] = x;
  __syncthreads();
  if (t == 0){
    int s2 = 0;
    for (int w = 0; w < 8; w++) s2 += wsum[w];
    basesh = atomicAdd(&hdr[0], s2);
  }
  __syncthreads();
  {
    int base = basesh + (x - cnt);
    for (int w = 0; w < wv; w++) base += wsum[w];
    for (int j = 0; j < cnt; j++){
      int pos = base + j;
      if (pos < CAND_CAP){ cand_vals[pos] = kv[j]; cand_idx[pos] = (b<<14)|(r<<7)|km[j]; }
    }
  }
  // 17-value block reduction
  float qv[17];
  qv[0]=cntf; qv[1]=wr;
  qv[2]=wr*rx; qv[3]=wr*ry; qv[4]=wr*rz;     // rc numerator
  qv[5]=p0; qv[6]=p1; qv[7]=p2;              // sc numerator (= sum e*src)
  qv[8]=p0*rx;  qv[9]=p0*ry;  qv[10]=p0*rz;  // M^[c][d] = sum e*src_c*ref_d
  qv[11]=p1*rx; qv[12]=p1*ry; qv[13]=p1*rz;
  qv[14]=p2*rx; qv[15]=p2*ry; qv[16]=p2*rz;
  for (int k = 0; k < 17; k++){
    float v = qv[k];
    for (int off2 = 32; off2 > 0; off2 >>= 1) v += __shfl_down(v, off2);
    if (lane == 0) red[wv][k] = v;
  }
  __syncthreads();
  if (t == 0){
    float tot[17];
    for (int k = 0; k < 17; k++){
      float s2 = 0.f;
      for (int w = 0; w < 8; w++) s2 += red[w][k];
      tot[k] = s2;
    }
    float Wm = tot[1];
    float denom = Wm + 1e-5f;
    float idenom = 1.f / denom;
    float s = Wm * idenom;
    float rcv[3] = { tot[2]*idenom, tot[3]*idenom, tot[4]*idenom };
    float scv[3] = { tot[5]*idenom, tot[6]*idenom, tot[7]*idenom };
    float* o = &Hsr[b*15];
    for (int c = 0; c < 3; c++)
      for (int d = 0; d < 3; d++)
        o[c*3+d] = tot[8 + c*3 + d]*idenom - (2.f - s)*scv[c]*rcv[d];
    o[9]=scv[0]; o[10]=scv[1]; o[11]=scv[2];
    o[12]=rcv[0]; o[13]=rcv[1]; o[14]=rcv[2];
    pcount[b] = (int)(tot[0] + 0.5f);
  }
}

// ---------------- K3: 512 Kabsch + single-block top-2048 + gather -------------
__global__ __launch_bounds__(1024) void k3_kernel(
    const int* hdr, const float* __restrict__ cand_vals, const int* __restrict__ cand_idx,
    const float* __restrict__ Hsr, float* __restrict__ localT,
    const float* __restrict__ refp, const float* __restrict__ srcp,
    float* sel_vals, int* sel_idx, float* sel_ref, float* sel_src)
{
  __shared__ int hist[2048];
  __shared__ int sh[8];
  __shared__ int eqidx[2048];
  __shared__ int selsh[LIMIT];
  const int t = threadIdx.x;

  // phase 0: per-batch local transforms (fused former k2)
  if (t < BB){
    const float* o = &Hsr[t*15];
    float H[3][3];
    for (int c = 0; c < 3; c++) for (int d = 0; d < 3; d++) H[c][d] = o[c*3+d];
    float R[3][3];
    kabsch_rot_f(H, R);
    float* T = &localT[t*12];
    for (int i = 0; i < 3; i++) for (int j = 0; j < 3; j++) T[i*3+j] = R[i][j];
    for (int i = 0; i < 3; i++)
      T[9+i] = o[12+i] - (R[i][0]*o[9] + R[i][1]*o[10] + R[i][2]*o[11]);
  }

  // phase 1: top-2048 by 3-pass radix over positive-float keys
  int Nc = hdr[0]; if (Nc > CAND_CAP) Nc = CAND_CAP;
  if (Nc <= LIMIT){
    for (int i = t; i < LIMIT; i += 1024){
      if (i < Nc){ float v = cand_vals[i]; int ix = cand_idx[i];
                   sel_vals[i] = v; sel_idx[i] = ix; selsh[i] = ix; }
      else       { sel_vals[i] = 0.f; sel_idx[i] = 0; selsh[i] = 0; }
    }
  } else {
    // pass 1: bits 31..21
    for (int i = t; i < 2048; i += 1024) hist[i] = 0;
    __syncthreads();
    for (int i = t; i < Nc; i += 1024)
      atomicAdd(&hist[__float_as_uint(cand_vals[i]) >> 21], 1);
    __syncthreads();
    if (t == 0){
      int cum = 0, bin = 0;
      for (int j = 2047; j >= 0; j--){ if (cum + hist[j] >= LIMIT){ bin = j; break; } cum += hist[j]; }
      sh[0] = bin; sh[1] = LIMIT - cum;
    }
    __syncthreads();
    unsigned bin1 = (unsigned)sh[0]; int need1 = sh[1];
    // pass 2: bits 20..10 within bin1
    for (int i = t; i < 2048; i += 1024) hist[i] = 0;
    __syncthreads();
    for (int i = t; i < Nc; i += 1024){
      unsigned k = __float_as_uint(cand_vals[i]);
      if ((k >> 21) == bin1) atomicAdd(&hist[(k >> 10) & 0x7FF], 1);
    }
    __syncthreads();
    if (t == 0){
      int cum = 0, bin = 0;
      for (int j = 2047; j >= 0; j--){ if (cum + hist[j] >= need1){ bin = j; break; } cum += hist[j]; }
      sh[2] = bin; sh[3] = need1 - cum;
    }
    __syncthreads();
    unsigned bin2 = (unsigned)sh[2]; int need2 = sh[3];
    unsigned pref2 = (bin1 << 11) | bin2;
    // pass 3: bits 9..0 within (bin1,bin2)
    for (int i = t; i < 2048; i += 1024) hist[i] = 0;
    __syncthreads();
    for (int i = t; i < Nc; i += 1024){
      unsigned k = __float_as_uint(cand_vals[i]);
      if ((k >> 10) == pref2) atomicAdd(&hist[k & 0x3FF], 1);
    }
    __syncthreads();
    if (t == 0){
      int cum = 0, bin = 0;
      for (int j = 1023; j >= 0; j--){ if (cum + hist[j] >= need2){ bin = j; break; } cum += hist[j]; }
      sh[4] = bin; sh[5] = need2 - cum; sh[6] = 0; sh[7] = 0;
    }
    __syncthreads();
    unsigned Tkey = (pref2 << 10) | (unsigned)sh[4];
    int needEq = sh[5];
    for (int i = t; i < Nc; i += 1024){
      float v = cand_vals[i];
      unsigned k = __float_as_uint(v);
      if (k > Tkey){
        int p = atomicAdd(&sh[6], 1);
        if (p < LIMIT){ sel_vals[p] = v; sel_idx[p] = cand_idx[i]; selsh[p] = cand_idx[i]; }
      } else if (k == Tkey){
        int p = atomicAdd(&sh[7], 1);
        if (p < 2048) eqidx[p] = cand_idx[i];
      }
    }
    __syncthreads();
    if (t == 0){
      int nAbove = sh[6]; if (nAbove > LIMIT) nAbove = LIMIT;
      int neq = sh[7]; if (neq > 2048) neq = 2048;
      int take = needEq; if (take > neq) take = neq; if (nAbove + take > LIMIT) take = LIMIT - nAbove;
      // tie-break: smallest flat index first (matches jax.lax.top_k)
      for (int j = 0; j < take; j++){
        int mi = j;
        for (int l = j+1; l < neq; l++) if (eqidx[l] < eqidx[mi]) mi = l;
        int tmp = eqidx[j]; eqidx[j] = eqidx[mi]; eqidx[mi] = tmp;
        sel_vals[nAbove + j] = __uint_as_float(Tkey);
        sel_idx[nAbove + j] = eqidx[j];
        selsh[nAbove + j] = eqidx[j];
      }
      for (int j = nAbove + take; j < LIMIT; j++){ sel_vals[j] = 0.f; sel_idx[j] = 0; selsh[j] = 0; }
    }
  }
  __syncthreads();
  // phase 2: gather correspondence points (from LDS copy of indices)
  for (int p = t; p < LIMIT; p += 1024){
    int idx = selsh[p];
    int b = idx >> 14, rr = (idx >> 7) & 127, ss = idx & 127;
    for (int c = 0; c < 3; c++){
      sel_ref[p*3+c] = refp[(b*NN+rr)*3+c];
      sel_src[p*3+c] = srcp[(b*NN+ss)*3+c];
    }
  }
}

// ---------------- K45: per-batch inlier counts + last-block argmax/refine -----
__global__ __launch_bounds__(256) void k45_kernel(
    const float* __restrict__ localT, const float* __restrict__ sel_vals,
    const float* __restrict__ sel_ref, const float* __restrict__ sel_src,
    const int* __restrict__ pcount, int* counts, int* hdr, float* out)
{
  __shared__ int ired[4];
  __shared__ int lastsh;
  __shared__ double dred[4][16];
  __shared__ long long lred[4];
  __shared__ float RT[12];
  __shared__ int sbest;
  const int b = blockIdx.x, t = threadIdx.x, lane = t & 63, wv = t >> 6;

  // ---- k4 phase: count inliers for batch b ----
  {
    const float* T = &localT[b*12];
    float R00=T[0],R01=T[1],R02=T[2],R10=T[3],R11=T[4],R12=T[5],R20=T[6],R21=T[7],R22=T[8];
    float tx=T[9], ty=T[10], tz=T[11];
    int c = 0;
    for (int p = t; p < LIMIT; p += 256){
      float v = sel_vals[p];
      if (!(v > 0.f)) continue;
      float sx=sel_src[p*3], sy=sel_src[p*3+1], sz=sel_src[p*3+2];
      float rx=sel_ref[p*3], ry=sel_ref[p*3+1], rz=sel_ref[p*3+2];
      float ax = R00*sx + R01*sy + R02*sz + tx;
      float ay = R10*sx + R11*sy + R12*sz + ty;
      float az = R20*sx + R21*sy + R22*sz + tz;
      float dx = rx-ax, dy = ry-ay, dz = rz-az;
      if (sqrtf(dx*dx + dy*dy + dz*dz) < 0.1f) c++;
    }
    for (int off2 = 32; off2 > 0; off2 >>= 1) c += __shfl_down(c, off2);
    if (lane == 0) ired[wv] = c;
    __syncthreads();
    if (t == 0){
      counts[b] = (pcount[b] >= 3) ? (ired[0]+ired[1]+ired[2]+ired[3]) : -1;
      __threadfence();                       // release counts[b]
      int d = atomicAdd(&hdr[6], 1);         // device-scope
      lastsh = (d == BB - 1) ? 1 : 0;
    }
    __syncthreads();
    if (!lastsh) return;
    __threadfence();                         // acquire all counts[]
  }

  // ---- k5 phase (only the last-finishing block): argmax + 5x Procrustes ----
  {
    long long key = (long long)0x8000000000000000LL;
    for (int bb = t; bb < BB; bb += 256){
      long long kk = ((long long)(counts[bb] + 2) << 32) | (long long)(511 - bb);
      if (kk > key) key = kk;
    }
    for (int off2 = 32; off2 > 0; off2 >>= 1){ long long o = __shfl_down(key, off2); if (o > key) key = o; }
    if (lane == 0) lred[wv] = key;
    __syncthreads();
    if (t == 0){
      long long m = lred[0];
      for (int w = 1; w < 4; w++) if (lred[w] > m) m = lred[w];
      sbest = 511 - (int)(m & 0xFFFFFFFFLL);
    }
    __syncthreads();
    if (t < 12) RT[t] = localT[sbest*12 + t];
    __syncthreads();

    for (int iter = 0; iter < 5; iter++){
      float R00=RT[0],R01=RT[1],R02=RT[2];
      float R10=RT[3],R11=RT[4],R12=RT[5];
      float R20=RT[6],R21=RT[7],R22=RT[8];
      float tx=RT[9], ty=RT[10], tz=RT[11];
      double a[16];
      for (int k = 0; k < 16; k++) a[k] = 0.0;
      for (int p = t; p < LIMIT; p += 256){
        float v = sel_vals[p];
        if (!(v > 0.f)) continue;
        float sx=sel_src[p*3], sy=sel_src[p*3+1], sz=sel_src[p*3+2];
        float rx=sel_ref[p*3], ry=sel_ref[p*3+1], rz=sel_ref[p*3+2];
        float ax = R00*sx + R01*sy + R02*sz + tx;
        float ay = R10*sx + R11*sy + R12*sz + ty;
        float az = R20*sx + R21*sy + R22*sz + tz;
        float dx = rx-ax, dy = ry-ay, dz = rz-az;
        if (sqrtf(dx*dx + dy*dy + dz*dz) < 0.1f){
          double w = (double)v;
          a[0] += w;
          a[1] += w*sx; a[2] += w*sy; a[3] += w*sz;
          a[4] += w*rx; a[5] += w*ry; a[6] += w*rz;
          a[7]  += w*sx*rx; a[8]  += w*sx*ry; a[9]  += w*sx*rz;
          a[10] += w*sy*rx; a[11] += w*sy*ry; a[12] += w*sy*rz;
          a[13] += w*sz*rx; a[14] += w*sz*ry; a[15] += w*sz*rz;
        }
      }
      for (int k = 0; k < 16; k++){
        double v = a[k];
        for (int off2 = 32; off2 > 0; off2 >>= 1) v += __shfl_down(v, off2);
        if (lane == 0) dred[wv][k] = v;
      }
      __syncthreads();
      if (t == 0){
        double tot[16];
        for (int k = 0; k < 16; k++) tot[k] = dred[0][k]+dred[1][k]+dred[2][k]+dred[3][k];
        double W = tot[0], denom = W + 1e-5;
        double inv = 1.0 / denom;
        double s = W * inv;
        double scv[3] = { tot[1]*inv, tot[2]*inv, tot[3]*inv };
        double rcv[3] = { tot[4]*inv, tot[5]*inv, tot[6]*inv };
        float H[3][3];
        for (int c = 0; c < 3; c++)
          for (int d = 0; d < 3; d++)
            H[c][d] = (float)(tot[7 + c*3 + d]*inv - (2.0 - s)*scv[c]*rcv[d]);
        float R[3][3];
        kabsch_rot_f(H, R);
        for (int i = 0; i < 3; i++) for (int j = 0; j < 3; j++) RT[i*3+j] = R[i][j];
        for (int i = 0; i < 3; i++)
          RT[9+i] = (float)(rcv[i] - ((double)R[i][0]*scv[0] + (double)R[i][1]*scv[1] + (double)R[i][2]*scv[2]));
      }
      __syncthreads();
    }
    if (t == 0){
      out[0]=RT[0];  out[1]=RT[1];  out[2]=RT[2];  out[3]=RT[9];
      out[4]=RT[3];  out[5]=RT[4];  out[6]=RT[5];  out[7]=RT[10];
      out[8]=RT[6];  out[9]=RT[7];  out[10]=RT[8]; out[11]=RT[11];
      out[12]=0.f; out[13]=0.f; out[14]=0.f; out[15]=1.f;
    }
  }
}

// ---------------- host launcher -----------------------------------------------
extern "C" void kernel_launch(void* const* d_in, const int* in_sizes, int n_in,
                              void* d_out, int out_size, void* d_ws, size_t ws_size,
                              hipStream_t stream){
  const float* score = (const float*)d_in[0];
  const float* refp  = (const float*)d_in[1];
  const float* srcp  = (const float*)d_in[2];
  const void*  rmask = d_in[3];
  const void*  smask = d_in[4];

  char* ws = (char*)d_ws;
  size_t off = 0;
  int* hdr = (int*)(ws + off);            off += 256;
  float* cand_vals = (float*)(ws + off);  off += (size_t)CAND_CAP*4;
  int* cand_idx = (int*)(ws + off);       off += (size_t)CAND_CAP*4;
  float* Hsr = (float*)(ws + off);        off += (size_t)BB*15*4;
  int* pcount = (int*)(ws + off);         off += (size_t)BB*4;
  float* localT = (float*)(ws + off);     off += (size_t)BB*12*4;
  float* sel_vals = (float*)(ws + off);   off += (size_t)LIMIT*4;
  int* sel_idx = (int*)(ws + off);        off += (size_t)LIMIT*4;
  float* sel_ref = (float*)(ws + off);    off += (size_t)LIMIT*3*4;
  float* sel_src = (float*)(ws + off);    off += (size_t)LIMIT*3*4;
  int* counts = (int*)(ws + off);         off += (size_t)BB*4;

  hipMemsetAsync(ws, 0, 256, stream);
  hipLaunchKernelGGL(k1_kernel, dim3(BB), dim3(512), 0, stream,
                     score, refp, srcp, rmask, smask, hdr, cand_vals, cand_idx, Hsr, pcount);
  hipLaunchKernelGGL(k3_kernel, dim3(1), dim3(1024), 0, stream,
                     hdr, cand_vals, cand_idx, Hsr, localT, refp, srcp,
                     sel_vals, sel_idx, sel_ref, sel_src);
  hipLaunchKernelGGL(k45_kernel, dim3(BB), dim3(256), 0, stream,
                     localT, sel_vals, sel_ref, sel_src, pcount, counts, hdr, (float*)d_out);
}

// Round 5
// 363.037 us; speedup vs baseline: 1.2622x; 1.2622x over previous
//
#include <hip/hip_runtime.h>
#include <math.h>

#define BB 512
#define NN 128
#define CAND_CAP (512*384)
#define LIMIT 2048

// ---------------- mask decode (int32 / byte / float32 robustness) -------------
__device__ inline bool read_mask(const void* p, int i, int mode){
  if (mode == 0) return ((const int*)p)[i] != 0;
  if (mode == 1) return ((const unsigned char*)p)[i] != 0;
  return ((const float*)p)[i] != 0.0f;
}

__device__ inline float fast_rcp(float x){ return __builtin_amdgcn_rcpf(x); }
__device__ inline float fast_rsq(float x){ return __builtin_amdgcn_rsqf(x); }

__device__ inline void top3_update(float v, float& a1, float& a2, float& a3){
  if (v > a1){ a3=a2; a2=a1; a1=v; }
  else if (v > a2){ a3=a2; a2=v; }
  else if (v > a3){ a3=v; }
}

// ---------------- fp32 Kabsch rotation from 3x3 covariance --------------------
__device__ void kabsch_rot_f(const float H[3][3], float R[3][3]){
  float S[3][3];
  for (int i = 0; i < 3; i++)
    for (int j = 0; j < 3; j++){
      float a = 0.f;
      for (int k = 0; k < 3; k++) a += H[k][i]*H[k][j];
      S[i][j] = a;
    }
  float V[3][3] = {{1,0,0},{0,1,0},{0,0,1}};
  for (int sweep = 0; sweep < 10; sweep++){
    float off  = S[0][1]*S[0][1] + S[0][2]*S[0][2] + S[1][2]*S[1][2];
    float base = S[0][0]*S[0][0] + S[1][1]*S[1][1] + S[2][2]*S[2][2];
    if (off <= base*1e-14f + 1e-36f) break;
    for (int p = 0; p < 2; p++)
      for (int q = p+1; q < 3; q++){
        float apq = S[p][q];
        if (fabsf(apq) <= 1e-30f) continue;
        float tau = (S[q][q] - S[p][p]) * fast_rcp(2.f*apq);
        float tt  = (tau >= 0.f ? 1.f : -1.f) * fast_rcp(fabsf(tau) + sqrtf(1.f + tau*tau));
        float c = fast_rsq(1.f + tt*tt), s = tt*c;
        for (int k = 0; k < 3; k++){ float a=S[k][p], b2=S[k][q]; S[k][p]=c*a-s*b2; S[k][q]=s*a+c*b2; }
        for (int k = 0; k < 3; k++){ float a=S[p][k], b2=S[q][k]; S[p][k]=c*a-s*b2; S[q][k]=s*a+c*b2; }
        for (int k = 0; k < 3; k++){ float a=V[k][p], b2=V[k][q]; V[k][p]=c*a-s*b2; V[k][q]=s*a+c*b2; }
      }
  }
  float lam[3] = { S[0][0], S[1][1], S[2][2] };
  int o0=0,o1=1,o2=2;
  if (lam[o0] < lam[o1]){ int x=o0;o0=o1;o1=x; }
  if (lam[o0] < lam[o2]){ int x=o0;o0=o2;o2=x; }
  if (lam[o1] < lam[o2]){ int x=o1;o1=o2;o2=x; }
  float v0[3]={V[0][o0],V[1][o0],V[2][o0]};
  float v1[3]={V[0][o1],V[1][o1],V[2][o1]};
  float v2[3]={V[0][o2],V[1][o2],V[2][o2]};
  float sig0 = sqrtf(fmaxf(lam[o0], 0.f));
  if (!(sig0 > 1e-12f)){
    for (int i = 0; i < 3; i++) for (int j = 0; j < 3; j++) R[i][j] = (i==j) ? 1.f : 0.f;
    return;
  }
  float u0[3],u1[3],u2[3];
  for (int i = 0; i < 3; i++) u0[i] = H[i][0]*v0[0] + H[i][1]*v0[1] + H[i][2]*v0[2];
  float d0 = u0[0]*u0[0]+u0[1]*u0[1]+u0[2]*u0[2];
  float in0 = fast_rsq(d0);
  for (int i = 0; i < 3; i++) u0[i] *= in0;
  for (int i = 0; i < 3; i++) u1[i] = H[i][0]*v1[0] + H[i][1]*v1[1] + H[i][2]*v1[2];
  float dp = u1[0]*u0[0]+u1[1]*u0[1]+u1[2]*u0[2];
  for (int i = 0; i < 3; i++) u1[i] -= dp*u0[i];
  float d1 = u1[0]*u1[0]+u1[1]*u1[1]+u1[2]*u1[2];
  float n1 = sqrtf(d1);
  if (n1 > sig0*1e-5f){
    float in1 = fast_rsq(d1);
    for (int i = 0; i < 3; i++) u1[i] *= in1;
  } else {
    int k = (fabsf(u0[0])<=fabsf(u0[1]) && fabsf(u0[0])<=fabsf(u0[2])) ? 0 : ((fabsf(u0[1])<=fabsf(u0[2])) ? 1 : 2);
    float e[3] = {0,0,0}; e[k] = 1.f;
    float d2 = e[0]*u0[0]+e[1]*u0[1]+e[2]*u0[2];
    for (int i = 0; i < 3; i++) u1[i] = e[i] - d2*u0[i];
    float nn = fast_rsq(u1[0]*u1[0]+u1[1]*u1[1]+u1[2]*u1[2]);
    for (int i = 0; i < 3; i++) u1[i] *= nn;
  }
  u2[0] = u0[1]*u1[2] - u0[2]*u1[1];
  u2[1] = u0[2]*u1[0] - u0[0]*u1[2];
  u2[2] = u0[0]*u1[1] - u0[1]*u1[0];
  float cx = v1[1]*v2[2] - v1[2]*v2[1];
  float cy = v1[2]*v2[0] - v1[0]*v2[2];
  float cz = v1[0]*v2[1] - v1[1]*v2[0];
  float detV = v0[0]*cx + v0[1]*cy + v0[2]*cz;  // det(U)=+1 by construction
  float dd = (detV >= 0.f) ? 1.f : -1.f;
  for (int i = 0; i < 3; i++)
    for (int j = 0; j < 3; j++)
      R[i][j] = v0[i]*u0[j] + v1[i]*u1[j] + dd*v2[i]*u2[j];
}

// ---------------- K1: raw-score mutual top-3, sparse exp, stats, candidates ---
// 512 threads: thread t -> row r = t&127, quarter q = t>>7 (32 cols/rows each)
__global__ __launch_bounds__(512, 4) void k1_kernel(
    const float* __restrict__ score, const float* __restrict__ refp,
    const float* __restrict__ srcp, const void* __restrict__ rmaskp,
    const void* __restrict__ smaskp, int* hdr, float* cand_vals, int* cand_idx,
    float* Hsr, int* pcount)
{
  __shared__ float tile[NN*NN];        // 64 KB raw-score tile
  __shared__ float part[4][NN][3];     // reused: col partials, then row partials
  __shared__ float c3sh[NN], r3sh[NN];
  __shared__ unsigned char smk[NN], rmk[NN];
  __shared__ float srcsh[NN*3];
  __shared__ float red[8][17];
  __shared__ int wsum[8];
  __shared__ int basesh;
  __shared__ int smode;
  const int b = blockIdx.x, t = threadIdx.x;
  const int r = t & 127, q = t >> 7;
  const int lane = t & 63, wv = t >> 6;

  // mode detect (wave 0): int32 0/1, byte, or float 0/1.0
  if (t < 64){
    unsigned v = ((const unsigned*)rmaskp)[t];
    bool n01 = !(v == 0u || v == 1u);
    bool nf  = !(v == 0u || v == 0x3F800000u);
    unsigned long long b01 = __ballot(n01), bf = __ballot(nf);
    if (t == 0) smode = (b01 == 0ull) ? 0 : ((bf == 0ull) ? 2 : 1);
  }

  // coalesced raw load (no exp!)
  {
    const float4* s4 = (const float4*)(score + (size_t)b*NN*NN);
    float4* t4 = (float4*)tile;
    for (int j = t; j < NN*NN/4; j += 512) t4[j] = s4[j];
  }
  __syncthreads();   // tile + smode ready

  if (t < NN){
    int mode = smode;
    smk[t] = read_mask(smaskp, b*NN + t, mode) ? 1 : 0;
    rmk[t] = read_mask(rmaskp, b*NN + t, mode) ? 1 : 0;
    srcsh[t*3+0] = srcp[(b*NN+t)*3+0];
    srcsh[t*3+1] = srcp[(b*NN+t)*3+1];
    srcsh[t*3+2] = srcp[(b*NN+t)*3+2];
  }
  // column partial top-3: column c=r, rows [q*32, q*32+32)
  {
    float a1=-1e30f, a2=-1e30f, a3=-1e30f;
    for (int i = 0; i < 32; i++){
      float v = tile[(q*32 + i)*NN + r];
      top3_update(v, a1, a2, a3);
    }
    part[q][r][0]=a1; part[q][r][1]=a2; part[q][r][2]=a3;
  }
  __syncthreads();
  if (t < NN){
    float m1=-1e30f, m2=-1e30f, m3=-1e30f;
    for (int qq = 0; qq < 4; qq++)
      for (int j = 0; j < 3; j++) top3_update(part[qq][t][j], m1, m2, m3);
    c3sh[t] = m3;
  }
  __syncthreads();
  // row partial top-3: row r, cols q*32 + ((r+i)&31)  (rotation: 2-way banks, free)
  {
    float a1=-1e30f, a2=-1e30f, a3=-1e30f;
    for (int i = 0; i < 32; i++){
      int c = q*32 + ((r + i) & 31);
      top3_update(tile[r*NN + c], a1, a2, a3);
    }
    part[q][r][0]=a1; part[q][r][1]=a2; part[q][r][2]=a3;
  }
  __syncthreads();
  if (t < NN){
    float m1=-1e30f, m2=-1e30f, m3=-1e30f;
    for (int qq = 0; qq < 4; qq++)
      for (int j = 0; j < 3; j++) top3_update(part[qq][t][j], m1, m2, m3);
    r3sh[t] = m3;
  }
  __syncthreads();

  // masked pass: mutual top-3 on RAW (exp monotone), expf only at survivors
  float wr = 0.f, p0 = 0.f, p1 = 0.f, p2 = 0.f, cntf = 0.f;
  float kv[3]; int km[3]; int cnt = 0;
  const float r3 = r3sh[r];
  const bool rmv = rmk[r] != 0;
  const float rx = refp[(b*NN+r)*3+0], ry = refp[(b*NN+r)*3+1], rz = refp[(b*NN+r)*3+2];
  for (int i = 0; i < 32; i++){
    int c = q*32 + ((r + i) & 31);
    float v = tile[r*NN + c];
    if (rmv && smk[c] && v >= r3 && v >= c3sh[c]){
      float e = expf(v);
      if (e > 0.05f){
        cntf += 1.f; wr += e;
        p0 += e*srcsh[c*3+0]; p1 += e*srcsh[c*3+1]; p2 += e*srcsh[c*3+2];
        if (cnt < 3){ kv[cnt] = e; km[cnt] = c; cnt++; }
      }
    }
  }
  // block-wide exclusive scan of cnt -> single atomic per block
  int x = cnt;
  for (int off2 = 1; off2 < 64; off2 <<= 1){ int y = __shfl_up(x, off2); if (lane >= off2) x += y; }
  if (lane == 63) wsum[wv] = x;
  __syncthreads();
  if (t == 0){
    int s2 = 0;
    for (int w = 0; w < 8; w++) s2 += wsum[w];
    basesh = atomicAdd(&hdr[0], s2);
  }
  __syncthreads();
  {
    int base = basesh + (x - cnt);
    for (int w = 0; w < wv; w++) base += wsum[w];
    for (int j = 0; j < cnt; j++){
      int pos = base + j;
      if (pos < CAND_CAP){ cand_vals[pos] = kv[j]; cand_idx[pos] = (b<<14)|(r<<7)|km[j]; }
    }
  }
  // 17-value block reduction
  float qv[17];
  qv[0]=cntf; qv[1]=wr;
  qv[2]=wr*rx; qv[3]=wr*ry; qv[4]=wr*rz;     // rc numerator
  qv[5]=p0; qv[6]=p1; qv[7]=p2;              // sc numerator (= sum e*src)
  qv[8]=p0*rx;  qv[9]=p0*ry;  qv[10]=p0*rz;  // M^[c][d] = sum e*src_c*ref_d
  qv[11]=p1*rx; qv[12]=p1*ry; qv[13]=p1*rz;
  qv[14]=p2*rx; qv[15]=p2*ry; qv[16]=p2*rz;
  for (int k = 0; k < 17; k++){
    float v = qv[k];
    for (int off2 = 32; off2 > 0; off2 >>= 1) v += __shfl_down(v, off2);
    if (lane == 0) red[wv][k] = v;
  }
  __syncthreads();
  if (t == 0){
    float tot[17];
    for (int k = 0; k < 17; k++){
      float s2 = 0.f;
      for (int w = 0; w < 8; w++) s2 += red[w][k];
      tot[k] = s2;
    }
    float Wm = tot[1];
    float denom = Wm + 1e-5f;
    float idenom = 1.f / denom;
    float s = Wm * idenom;
    float rcv[3] = { tot[2]*idenom, tot[3]*idenom, tot[4]*idenom };
    float scv[3] = { tot[5]*idenom, tot[6]*idenom, tot[7]*idenom };
    float* o = &Hsr[b*15];
    for (int c = 0; c < 3; c++)
      for (int d = 0; d < 3; d++)
        o[c*3+d] = tot[8 + c*3 + d]*idenom - (2.f - s)*scv[c]*rcv[d];
    o[9]=scv[0]; o[10]=scv[1]; o[11]=scv[2];
    o[12]=rcv[0]; o[13]=rcv[1]; o[14]=rcv[2];
    pcount[b] = (int)(tot[0] + 0.5f);
  }
}

// ---------------- K3: 512 Kabsch + single-block top-2048 + gather -------------
__global__ __launch_bounds__(1024) void k3_kernel(
    const int* hdr, const float* __restrict__ cand_vals, const int* __restrict__ cand_idx,
    const float* __restrict__ Hsr, float* __restrict__ localT,
    const float* __restrict__ refp, const float* __restrict__ srcp,
    float* sel_vals, int* sel_idx, float* sel_ref, float* sel_src)
{
  __shared__ int hist[2048];
  __shared__ int sh[8];
  __shared__ int eqidx[2048];
  __shared__ int selsh[LIMIT];
  __shared__ int wtot[16];
  __shared__ int bpair[2];
  const int t = threadIdx.x;
  const int lane = t & 63, wv = t >> 6;

  // phase 0: per-batch local transforms (fused former k2)
  if (t < BB){
    const float* o = &Hsr[t*15];
    float H[3][3];
    for (int c = 0; c < 3; c++) for (int d = 0; d < 3; d++) H[c][d] = o[c*3+d];
    float R[3][3];
    kabsch_rot_f(H, R);
    float* T = &localT[t*12];
    for (int i = 0; i < 3; i++) for (int j = 0; j < 3; j++) T[i*3+j] = R[i][j];
    for (int i = 0; i < 3; i++)
      T[9+i] = o[12+i] - (R[i][0]*o[9] + R[i][1]*o[10] + R[i][2]*o[11]);
  }

  // phase 1: top-2048 by 3-pass radix over positive-float keys
  int Nc = hdr[0]; if (Nc > CAND_CAP) Nc = CAND_CAP;
  if (Nc <= LIMIT){
    for (int i = t; i < LIMIT; i += 1024){
      if (i < Nc){ float v = cand_vals[i]; int ix = cand_idx[i];
                   sel_vals[i] = v; sel_idx[i] = ix; selsh[i] = ix; }
      else       { sel_vals[i] = 0.f; sel_idx[i] = 0; selsh[i] = 0; }
    }
  } else {
    // ---- parallel boundary-find lambda over hist[NB], NB in {2048, 1024} ----
    // computes: bin = largest j with suffix-sum S(j) >= need; leftover = need - S(j+1)
    auto find_boundary = [&](int NB, int need){
      int k = NB >> 10;                    // elems per thread (1 or 2)
      int base_i = t * k;
      int gv[2]; int local = 0;
      for (int e = 0; e < k; e++){ gv[e] = hist[NB-1-(base_i+e)]; local += gv[e]; }
      int incl = local;
      for (int off = 1; off < 64; off <<= 1){ int y = __shfl_up(incl, off); if (lane >= off) incl += y; }
      if (lane == 63) wtot[wv] = incl;
      __syncthreads();
      int wbase = 0;
      for (int w = 0; w < wv; w++) wbase += wtot[w];
      int P_prev = wbase + incl - local;   // prefix (reversed) exclusive
      for (int e = 0; e < k; e++){
        int P = P_prev + gv[e];
        if (P >= need && P_prev < need){   // unique thread+elem
          bpair[0] = NB-1-(base_i+e); bpair[1] = need - P_prev;
        }
        P_prev = P;
      }
      __syncthreads();
    };
    // pass 1: bits 31..21
    for (int i = t; i < 2048; i += 1024) hist[i] = 0;
    __syncthreads();
    for (int i = t; i < Nc; i += 1024)
      atomicAdd(&hist[__float_as_uint(cand_vals[i]) >> 21], 1);
    __syncthreads();
    find_boundary(2048, LIMIT);
    unsigned bin1 = (unsigned)bpair[0]; int need1 = bpair[1];
    __syncthreads();
    // pass 2: bits 20..10 within bin1
    for (int i = t; i < 2048; i += 1024) hist[i] = 0;
    __syncthreads();
    for (int i = t; i < Nc; i += 1024){
      unsigned k = __float_as_uint(cand_vals[i]);
      if ((k >> 21) == bin1) atomicAdd(&hist[(k >> 10) & 0x7FF], 1);
    }
    __syncthreads();
    find_boundary(2048, need1);
    unsigned bin2 = (unsigned)bpair[0]; int need2 = bpair[1];
    unsigned pref2 = (bin1 << 11) | bin2;
    __syncthreads();
    // pass 3: bits 9..0 within (bin1,bin2)
    for (int i = t; i < 2048; i += 1024) hist[i] = 0;
    __syncthreads();
    for (int i = t; i < Nc; i += 1024){
      unsigned k = __float_as_uint(cand_vals[i]);
      if ((k >> 10) == pref2) atomicAdd(&hist[k & 0x3FF], 1);
    }
    __syncthreads();
    find_boundary(1024, need2);
    unsigned Tkey = (pref2 << 10) | (unsigned)bpair[0];
    int needEq = bpair[1];
    if (t == 0){ sh[6] = 0; sh[7] = 0; }
    __syncthreads();
    for (int i = t; i < Nc; i += 1024){
      float v = cand_vals[i];
      unsigned k = __float_as_uint(v);
      if (k > Tkey){
        int p = atomicAdd(&sh[6], 1);
        if (p < LIMIT){ sel_vals[p] = v; sel_idx[p] = cand_idx[i]; selsh[p] = cand_idx[i]; }
      } else if (k == Tkey){
        int p = atomicAdd(&sh[7], 1);
        if (p < 2048) eqidx[p] = cand_idx[i];
      }
    }
    __syncthreads();
    if (t == 0){
      int nAbove = sh[6]; if (nAbove > LIMIT) nAbove = LIMIT;
      int neq = sh[7]; if (neq > 2048) neq = 2048;
      int take = needEq; if (take > neq) take = neq; if (nAbove + take > LIMIT) take = LIMIT - nAbove;
      // tie-break: smallest flat index first (matches jax.lax.top_k)
      for (int j = 0; j < take; j++){
        int mi = j;
        for (int l = j+1; l < neq; l++) if (eqidx[l] < eqidx[mi]) mi = l;
        int tmp = eqidx[j]; eqidx[j] = eqidx[mi]; eqidx[mi] = tmp;
        sel_vals[nAbove + j] = __uint_as_float(Tkey);
        sel_idx[nAbove + j] = eqidx[j];
        selsh[nAbove + j] = eqidx[j];
      }
      for (int j = nAbove + take; j < LIMIT; j++){ sel_vals[j] = 0.f; sel_idx[j] = 0; selsh[j] = 0; }
    }
  }
  __syncthreads();
  // phase 2: gather correspondence points (from LDS copy of indices)
  for (int p = t; p < LIMIT; p += 1024){
    int idx = selsh[p];
    int b = idx >> 14, rr = (idx >> 7) & 127, ss = idx & 127;
    for (int c = 0; c < 3; c++){
      sel_ref[p*3+c] = refp[(b*NN+rr)*3+c];
      sel_src[p*3+c] = srcp[(b*NN+ss)*3+c];
    }
  }
}

// ---------------- K45: per-batch inlier counts + last-block argmax/refine -----
__global__ __launch_bounds__(256) void k45_kernel(
    const float* __restrict__ localT, const float* __restrict__ sel_vals,
    const float* __restrict__ sel_ref, const float* __restrict__ sel_src,
    const int* __restrict__ pcount, int* counts, int* hdr, float* out)
{
  __shared__ int ired[4];
  __shared__ int lastsh;
  __shared__ double dred[4][16];
  __shared__ long long lred[4];
  __shared__ float RT[12];
  __shared__ int sbest;
  const int b = blockIdx.x, t = threadIdx.x, lane = t & 63, wv = t >> 6;

  // ---- k4 phase: count inliers for batch b ----
  {
    const float* T = &localT[b*12];
    float R00=T[0],R01=T[1],R02=T[2],R10=T[3],R11=T[4],R12=T[5],R20=T[6],R21=T[7],R22=T[8];
    float tx=T[9], ty=T[10], tz=T[11];
    int c = 0;
    for (int p = t; p < LIMIT; p += 256){
      float v = sel_vals[p];
      if (!(v > 0.f)) continue;
      float sx=sel_src[p*3], sy=sel_src[p*3+1], sz=sel_src[p*3+2];
      float rx=sel_ref[p*3], ry=sel_ref[p*3+1], rz=sel_ref[p*3+2];
      float ax = R00*sx + R01*sy + R02*sz + tx;
      float ay = R10*sx + R11*sy + R12*sz + ty;
      float az = R20*sx + R21*sy + R22*sz + tz;
      float dx = rx-ax, dy = ry-ay, dz = rz-az;
      if (sqrtf(dx*dx + dy*dy + dz*dz) < 0.1f) c++;
    }
    for (int off2 = 32; off2 > 0; off2 >>= 1) c += __shfl_down(c, off2);
    if (lane == 0) ired[wv] = c;
    __syncthreads();
    if (t == 0){
      counts[b] = (pcount[b] >= 3) ? (ired[0]+ired[1]+ired[2]+ired[3]) : -1;
      __threadfence();                       // release counts[b]
      int d = atomicAdd(&hdr[6], 1);         // device-scope
      lastsh = (d == BB - 1) ? 1 : 0;
    }
    __syncthreads();
    if (!lastsh) return;
    __threadfence();                         // acquire all counts[]
  }

  // ---- k5 phase (only the last-finishing block): argmax + 5x Procrustes ----
  {
    long long key = (long long)0x8000000000000000LL;
    for (int bb = t; bb < BB; bb += 256){
      long long kk = ((long long)(counts[bb] + 2) << 32) | (long long)(511 - bb);
      if (kk > key) key = kk;
    }
    for (int off2 = 32; off2 > 0; off2 >>= 1){ long long o = __shfl_down(key, off2); if (o > key) key = o; }
    if (lane == 0) lred[wv] = key;
    __syncthreads();
    if (t == 0){
      long long m = lred[0];
      for (int w = 1; w < 4; w++) if (lred[w] > m) m = lred[w];
      sbest = 511 - (int)(m & 0xFFFFFFFFLL);
    }
    __syncthreads();
    if (t < 12) RT[t] = localT[sbest*12 + t];
    __syncthreads();

    for (int iter = 0; iter < 5; iter++){
      float R00=RT[0],R01=RT[1],R02=RT[2];
      float R10=RT[3],R11=RT[4],R12=RT[5];
      float R20=RT[6],R21=RT[7],R22=RT[8];
      float tx=RT[9], ty=RT[10], tz=RT[11];
      double a[16];
      for (int k = 0; k < 16; k++) a[k] = 0.0;
      for (int p = t; p < LIMIT; p += 256){
        float v = sel_vals[p];
        if (!(v > 0.f)) continue;
        float sx=sel_src[p*3], sy=sel_src[p*3+1], sz=sel_src[p*3+2];
        float rx=sel_ref[p*3], ry=sel_ref[p*3+1], rz=sel_ref[p*3+2];
        float ax = R00*sx + R01*sy + R02*sz + tx;
        float ay = R10*sx + R11*sy + R12*sz + ty;
        float az = R20*sx + R21*sy + R22*sz + tz;
        float dx = rx-ax, dy = ry-ay, dz = rz-az;
        if (sqrtf(dx*dx + dy*dy + dz*dz) < 0.1f){
          double w = (double)v;
          a[0] += w;
          a[1] += w*sx; a[2] += w*sy; a[3] += w*sz;
          a[4] += w*rx; a[5] += w*ry; a[6] += w*rz;
          a[7]  += w*sx*rx; a[8]  += w*sx*ry; a[9]  += w*sx*rz;
          a[10] += w*sy*rx; a[11] += w*sy*ry; a[12] += w*sy*rz;
          a[13] += w*sz*rx; a[14] += w*sz*ry; a[15] += w*sz*rz;
        }
      }
      for (int k = 0; k < 16; k++){
        double v = a[k];
        for (int off2 = 32; off2 > 0; off2 >>= 1) v += __shfl_down(v, off2);
        if (lane == 0) dred[wv][k] = v;
      }
      __syncthreads();
      if (t == 0){
        double tot[16];
        for (int k = 0; k < 16; k++) tot[k] = dred[0][k]+dred[1][k]+dred[2][k]+dred[3][k];
        double W = tot[0], denom = W + 1e-5;
        double inv = 1.0 / denom;
        double s = W * inv;
        double scv[3] = { tot[1]*inv, tot[2]*inv, tot[3]*inv };
        double rcv[3] = { tot[4]*inv, tot[5]*inv, tot[6]*inv };
        float H[3][3];
        for (int c = 0; c < 3; c++)
          for (int d = 0; d < 3; d++)
            H[c][d] = (float)(tot[7 + c*3 + d]*inv - (2.0 - s)*scv[c]*rcv[d]);
        float R[3][3];
        kabsch_rot_f(H, R);
        for (int i = 0; i < 3; i++) for (int j = 0; j < 3; j++) RT[i*3+j] = R[i][j];
        for (int i = 0; i < 3; i++)
          RT[9+i] = (float)(rcv[i] - ((double)R[i][0]*scv[0] + (double)R[i][1]*scv[1] + (double)R[i][2]*scv[2]));
      }
      __syncthreads();
    }
    if (t == 0){
      out[0]=RT[0];  out[1]=RT[1];  out[2]=RT[2];  out[3]=RT[9];
      out[4]=RT[3];  out[5]=RT[4];  out[6]=RT[5];  out[7]=RT[10];
      out[8]=RT[6];  out[9]=RT[7];  out[10]=RT[8]; out[11]=RT[11];
      out[12]=0.f; out[13]=0.f; out[14]=0.f; out[15]=1.f;
    }
  }
}

// ---------------- host launcher -----------------------------------------------
extern "C" void kernel_launch(void* const* d_in, const int* in_sizes, int n_in,
                              void* d_out, int out_size, void* d_ws, size_t ws_size,
                              hipStream_t stream){
  const float* score = (const float*)d_in[0];
  const float* refp  = (const float*)d_in[1];
  const float* srcp  = (const float*)d_in[2];
  const void*  rmask = d_in[3];
  const void*  smask = d_in[4];

  char* ws = (char*)d_ws;
  size_t off = 0;
  int* hdr = (int*)(ws + off);            off += 256;
  float* cand_vals = (float*)(ws + off);  off += (size_t)CAND_CAP*4;
  int* cand_idx = (int*)(ws + off);       off += (size_t)CAND_CAP*4;
  float* Hsr = (float*)(ws + off);        off += (size_t)BB*15*4;
  int* pcount = (int*)(ws + off);         off += (size_t)BB*4;
  float* localT = (float*)(ws + off);     off += (size_t)BB*12*4;
  float* sel_vals = (float*)(ws + off);   off += (size_t)LIMIT*4;
  int* sel_idx = (int*)(ws + off);        off += (size_t)LIMIT*4;
  float* sel_ref = (float*)(ws + off);    off += (size_t)LIMIT*3*4;
  float* sel_src = (float*)(ws + off);    off += (size_t)LIMIT*3*4;
  int* counts = (int*)(ws + off);         off += (size_t)BB*4;

  hipMemsetAsync(ws, 0, 256, stream);
  hipLaunchKernelGGL(k1_kernel, dim3(BB), dim3(512), 0, stream,
                     score, refp, srcp, rmask, smask, hdr, cand_vals, cand_idx, Hsr, pcount);
  hipLaunchKernelGGL(k3_kernel, dim3(1), dim3(1024), 0, stream,
                     hdr, cand_vals, cand_idx, Hsr, localT, refp, srcp,
                     sel_vals, sel_idx, sel_ref, sel_src);
  hipLaunchKernelGGL(k45_kernel, dim3(BB), dim3(256), 0, stream,
                     localT, sel_vals, sel_ref, sel_src, pcount, counts, hdr, (float*)d_out);
}

// Round 6
// 358.532 us; speedup vs baseline: 1.2781x; 1.0126x over previous
//
#include <hip/hip_runtime.h>
#include <math.h>

#define BB 512
#define NN 128
#define CAND_CAP (512*384)
#define LIMIT 2048

// ---------------- mask decode (int32 / byte / float32 robustness) -------------
__device__ inline bool read_mask(const void* p, int i, int mode){
  if (mode == 0) return ((const int*)p)[i] != 0;
  if (mode == 1) return ((const unsigned char*)p)[i] != 0;
  return ((const float*)p)[i] != 0.0f;
}

__device__ inline float fast_rcp(float x){ return __builtin_amdgcn_rcpf(x); }
__device__ inline float fast_rsq(float x){ return __builtin_amdgcn_rsqf(x); }

__device__ inline void top3_update(float v, float& a1, float& a2, float& a3){
  if (v > a1){ a3=a2; a2=a1; a1=v; }
  else if (v > a2){ a3=a2; a2=v; }
  else if (v > a3){ a3=v; }
}

// ---------------- fp32 Kabsch rotation from 3x3 covariance --------------------
// NO dynamic indexing anywhere: all loops fully unrolled w/ constant indices so
// SROA keeps S,V,H,R in VGPRs (round-5 version spilled to scratch: VGPR=28,
// 147us serial latency). Eigen-sort done as compare-swaps on scalars.
__device__ void kabsch_rot_f(const float H[3][3], float R[3][3]){
  float S[3][3];
#pragma unroll
  for (int i = 0; i < 3; i++)
#pragma unroll
    for (int j = 0; j < 3; j++){
      float a = 0.f;
#pragma unroll
      for (int k = 0; k < 3; k++) a += H[k][i]*H[k][j];
      S[i][j] = a;
    }
  float V[3][3] = {{1,0,0},{0,1,0},{0,0,1}};
  for (int sweep = 0; sweep < 10; sweep++){
    float off  = S[0][1]*S[0][1] + S[0][2]*S[0][2] + S[1][2]*S[1][2];
    float base = S[0][0]*S[0][0] + S[1][1]*S[1][1] + S[2][2]*S[2][2];
    if (off <= base*1e-14f + 1e-36f) break;
#pragma unroll
    for (int pq = 0; pq < 3; pq++){
      const int p = (pq == 2) ? 1 : 0;      // pairs: (0,1), (0,2), (1,2)
      const int q = (pq == 0) ? 1 : 2;
      float apq = S[p][q];
      if (fabsf(apq) > 1e-30f){
        float tau = (S[q][q] - S[p][p]) * fast_rcp(2.f*apq);
        float tt  = (tau >= 0.f ? 1.f : -1.f) * fast_rcp(fabsf(tau) + sqrtf(1.f + tau*tau));
        float c = fast_rsq(1.f + tt*tt), s = tt*c;
#pragma unroll
        for (int k = 0; k < 3; k++){ float a=S[k][p], b2=S[k][q]; S[k][p]=c*a-s*b2; S[k][q]=s*a+c*b2; }
#pragma unroll
        for (int k = 0; k < 3; k++){ float a=S[p][k], b2=S[q][k]; S[p][k]=c*a-s*b2; S[q][k]=s*a+c*b2; }
#pragma unroll
        for (int k = 0; k < 3; k++){ float a=V[k][p], b2=V[k][q]; V[k][p]=c*a-s*b2; V[k][q]=s*a+c*b2; }
      }
    }
  }
  // eigen columns as scalars; sort descending by eigenvalue via compare-swaps
  float l0=S[0][0], l1=S[1][1], l2=S[2][2];
  float a0=V[0][0], a1=V[1][0], a2=V[2][0];   // column 0
  float b0=V[0][1], b1=V[1][1], b2=V[2][1];   // column 1
  float c0=V[0][2], c1=V[1][2], c2=V[2][2];   // column 2
  if (l0 < l1){ float x; x=l0;l0=l1;l1=x; x=a0;a0=b0;b0=x; x=a1;a1=b1;b1=x; x=a2;a2=b2;b2=x; }
  if (l0 < l2){ float x; x=l0;l0=l2;l2=x; x=a0;a0=c0;c0=x; x=a1;a1=c1;c1=x; x=a2;a2=c2;c2=x; }
  if (l1 < l2){ float x; x=l1;l1=l2;l2=x; x=b0;b0=c0;c0=x; x=b1;b1=c1;c1=x; x=b2;b2=c2;c2=x; }
  float sig0 = sqrtf(fmaxf(l0, 0.f));
  if (!(sig0 > 1e-12f)){
#pragma unroll
    for (int i = 0; i < 3; i++)
#pragma unroll
      for (int j = 0; j < 3; j++) R[i][j] = (i==j) ? 1.f : 0.f;
    return;
  }
  // u0 = normalize(H v0)
  float u0x = H[0][0]*a0 + H[0][1]*a1 + H[0][2]*a2;
  float u0y = H[1][0]*a0 + H[1][1]*a1 + H[1][2]*a2;
  float u0z = H[2][0]*a0 + H[2][1]*a1 + H[2][2]*a2;
  float in0 = fast_rsq(u0x*u0x + u0y*u0y + u0z*u0z);
  u0x *= in0; u0y *= in0; u0z *= in0;
  // u1 = orthonormalize(H v1) against u0
  float u1x = H[0][0]*b0 + H[0][1]*b1 + H[0][2]*b2;
  float u1y = H[1][0]*b0 + H[1][1]*b1 + H[1][2]*b2;
  float u1z = H[2][0]*b0 + H[2][1]*b1 + H[2][2]*b2;
  float dp = u1x*u0x + u1y*u0y + u1z*u0z;
  u1x -= dp*u0x; u1y -= dp*u0y; u1z -= dp*u0z;
  float d1 = u1x*u1x + u1y*u1y + u1z*u1z;
  if (sqrtf(d1) > sig0*1e-5f){
    float in1 = fast_rsq(d1);
    u1x *= in1; u1y *= in1; u1z *= in1;
  } else {
    float au0 = fabsf(u0x), au1 = fabsf(u0y), au2 = fabsf(u0z);
    float e0 = 0.f, e1 = 0.f, e2 = 0.f;
    if (au0 <= au1 && au0 <= au2) e0 = 1.f; else if (au1 <= au2) e1 = 1.f; else e2 = 1.f;
    float d2 = e0*u0x + e1*u0y + e2*u0z;
    u1x = e0 - d2*u0x; u1y = e1 - d2*u0y; u1z = e2 - d2*u0z;
    float nn = fast_rsq(u1x*u1x + u1y*u1y + u1z*u1z);
    u1x *= nn; u1y *= nn; u1z *= nn;
  }
  float u2x = u0y*u1z - u0z*u1y;
  float u2y = u0z*u1x - u0x*u1z;
  float u2z = u0x*u1y - u0y*u1x;
  // d = sign(det V)   (det U = +1 by construction)
  float cxv = b1*c2 - b2*c1;
  float cyv = b2*c0 - b0*c2;
  float czv = b0*c1 - b1*c0;
  float detV = a0*cxv + a1*cyv + a2*czv;
  float dd = (detV >= 0.f) ? 1.f : -1.f;
  float w2x = dd*u2x, w2y = dd*u2y, w2z = dd*u2z;
  R[0][0]=a0*u0x + b0*u1x + c0*w2x;  R[0][1]=a0*u0y + b0*u1y + c0*w2y;  R[0][2]=a0*u0z + b0*u1z + c0*w2z;
  R[1][0]=a1*u0x + b1*u1x + c1*w2x;  R[1][1]=a1*u0y + b1*u1y + c1*w2y;  R[1][2]=a1*u0z + b1*u1z + c1*w2z;
  R[2][0]=a2*u0x + b2*u1x + c2*w2x;  R[2][1]=a2*u0y + b2*u1y + c2*w2y;  R[2][2]=a2*u0z + b2*u1z + c2*w2z;
}

// ---------------- K1: raw-score mutual top-3, sparse exp, stats, candidates ---
// 512 threads: thread t -> row r = t&127, quarter q = t>>7 (32 cols/rows each)
__global__ __launch_bounds__(512, 4) void k1_kernel(
    const float* __restrict__ score, const float* __restrict__ refp,
    const float* __restrict__ srcp, const void* __restrict__ rmaskp,
    const void* __restrict__ smaskp, int* hdr, float* cand_vals, int* cand_idx,
    float* Hsr, int* pcount)
{
  __shared__ float tile[NN*NN];        // 64 KB raw-score tile
  __shared__ float part[4][NN][3];     // reused: col partials, then row partials
  __shared__ float c3sh[NN], r3sh[NN];
  __shared__ unsigned char smk[NN], rmk[NN];
  __shared__ float srcsh[NN*3];
  __shared__ float red[8][17];
  __shared__ int wsum[8];
  __shared__ int basesh;
  __shared__ int smode;
  const int b = blockIdx.x, t = threadIdx.x;
  const int r = t & 127, q = t >> 7;
  const int lane = t & 63, wv = t >> 6;

  // mode detect (wave 0): int32 0/1, byte, or float 0/1.0
  if (t < 64){
    unsigned v = ((const unsigned*)rmaskp)[t];
    bool n01 = !(v == 0u || v == 1u);
    bool nf  = !(v == 0u || v == 0x3F800000u);
    unsigned long long b01 = __ballot(n01), bf = __ballot(nf);
    if (t == 0) smode = (b01 == 0ull) ? 0 : ((bf == 0ull) ? 2 : 1);
  }

  // coalesced raw load (no exp!)
  {
    const float4* s4 = (const float4*)(score + (size_t)b*NN*NN);
    float4* t4 = (float4*)tile;
    for (int j = t; j < NN*NN/4; j += 512) t4[j] = s4[j];
  }
  __syncthreads();   // tile + smode ready

  if (t < NN){
    int mode = smode;
    smk[t] = read_mask(smaskp, b*NN + t, mode) ? 1 : 0;
    rmk[t] = read_mask(rmaskp, b*NN + t, mode) ? 1 : 0;
    srcsh[t*3+0] = srcp[(b*NN+t)*3+0];
    srcsh[t*3+1] = srcp[(b*NN+t)*3+1];
    srcsh[t*3+2] = srcp[(b*NN+t)*3+2];
  }
  // column partial top-3: column c=r, rows [q*32, q*32+32)
  {
    float a1=-1e30f, a2=-1e30f, a3=-1e30f;
    for (int i = 0; i < 32; i++){
      float v = tile[(q*32 + i)*NN + r];
      top3_update(v, a1, a2, a3);
    }
    part[q][r][0]=a1; part[q][r][1]=a2; part[q][r][2]=a3;
  }
  __syncthreads();
  if (t < NN){
    float m1=-1e30f, m2=-1e30f, m3=-1e30f;
#pragma unroll
    for (int qq = 0; qq < 4; qq++)
#pragma unroll
      for (int j = 0; j < 3; j++) top3_update(part[qq][t][j], m1, m2, m3);
    c3sh[t] = m3;
  }
  __syncthreads();
  // row partial top-3: row r, cols q*32 + ((r+i)&31)  (rotation: 2-way banks, free)
  {
    float a1=-1e30f, a2=-1e30f, a3=-1e30f;
    for (int i = 0; i < 32; i++){
      int c = q*32 + ((r + i) & 31);
      top3_update(tile[r*NN + c], a1, a2, a3);
    }
    part[q][r][0]=a1; part[q][r][1]=a2; part[q][r][2]=a3;
  }
  __syncthreads();
  if (t < NN){
    float m1=-1e30f, m2=-1e30f, m3=-1e30f;
#pragma unroll
    for (int qq = 0; qq < 4; qq++)
#pragma unroll
      for (int j = 0; j < 3; j++) top3_update(part[qq][t][j], m1, m2, m3);
    r3sh[t] = m3;
  }
  __syncthreads();

  // masked pass: mutual top-3 on RAW (exp monotone), expf only at survivors
  float wr = 0.f, p0 = 0.f, p1 = 0.f, p2 = 0.f, cntf = 0.f;
  float kv[3]; int km[3]; int cnt = 0;
  const float r3 = r3sh[r];
  const bool rmv = rmk[r] != 0;
  const float rx = refp[(b*NN+r)*3+0], ry = refp[(b*NN+r)*3+1], rz = refp[(b*NN+r)*3+2];
  for (int i = 0; i < 32; i++){
    int c = q*32 + ((r + i) & 31);
    float v = tile[r*NN + c];
    if (rmv && smk[c] && v >= r3 && v >= c3sh[c]){
      float e = expf(v);
      if (e > 0.05f){
        cntf += 1.f; wr += e;
        p0 += e*srcsh[c*3+0]; p1 += e*srcsh[c*3+1]; p2 += e*srcsh[c*3+2];
        if (cnt < 3){ kv[cnt] = e; km[cnt] = c; cnt++; }
      }
    }
  }
  // block-wide exclusive scan of cnt -> single atomic per block
  int x = cnt;
  for (int off2 = 1; off2 < 64; off2 <<= 1){ int y = __shfl_up(x, off2); if (lane >= off2) x += y; }
  if (lane == 63) wsum[wv] = x;
  __syncthreads();
  if (t == 0){
    int s2 = 0;
#pragma unroll
    for (int w = 0; w < 8; w++) s2 += wsum[w];
    basesh = atomicAdd(&hdr[0], s2);
  }
  __syncthreads();
  {
    int base = basesh + (x - cnt);
    for (int w = 0; w < wv; w++) base += wsum[w];
    for (int j = 0; j < cnt; j++){
      int pos = base + j;
      if (pos < CAND_CAP){ cand_vals[pos] = kv[j]; cand_idx[pos] = (b<<14)|(r<<7)|km[j]; }
    }
  }
  // 17-value block reduction
  float qv[17];
  qv[0]=cntf; qv[1]=wr;
  qv[2]=wr*rx; qv[3]=wr*ry; qv[4]=wr*rz;     // rc numerator
  qv[5]=p0; qv[6]=p1; qv[7]=p2;              // sc numerator (= sum e*src)
  qv[8]=p0*rx;  qv[9]=p0*ry;  qv[10]=p0*rz;  // M^[c][d] = sum e*src_c*ref_d
  qv[11]=p1*rx; qv[12]=p1*ry; qv[13]=p1*rz;
  qv[14]=p2*rx; qv[15]=p2*ry; qv[16]=p2*rz;
#pragma unroll
  for (int k = 0; k < 17; k++){
    float v = qv[k];
    for (int off2 = 32; off2 > 0; off2 >>= 1) v += __shfl_down(v, off2);
    if (lane == 0) red[wv][k] = v;
  }
  __syncthreads();
  if (t == 0){
    float tot[17];
#pragma unroll
    for (int k = 0; k < 17; k++){
      float s2 = 0.f;
#pragma unroll
      for (int w = 0; w < 8; w++) s2 += red[w][k];
      tot[k] = s2;
    }
    float Wm = tot[1];
    float denom = Wm + 1e-5f;
    float idenom = 1.f / denom;
    float s = Wm * idenom;
    float rcv[3] = { tot[2]*idenom, tot[3]*idenom, tot[4]*idenom };
    float scv[3] = { tot[5]*idenom, tot[6]*idenom, tot[7]*idenom };
    float* o = &Hsr[b*15];
#pragma unroll
    for (int c = 0; c < 3; c++)
#pragma unroll
      for (int d = 0; d < 3; d++)
        o[c*3+d] = tot[8 + c*3 + d]*idenom - (2.f - s)*scv[c]*rcv[d];
    o[9]=scv[0]; o[10]=scv[1]; o[11]=scv[2];
    o[12]=rcv[0]; o[13]=rcv[1]; o[14]=rcv[2];
    pcount[b] = (int)(tot[0] + 0.5f);
  }
}

// ---------------- K3: 512 Kabsch + single-block top-2048 + gather -------------
__global__ __launch_bounds__(1024) void k3_kernel(
    const int* hdr, const float* __restrict__ cand_vals, const int* __restrict__ cand_idx,
    const float* __restrict__ Hsr, float* __restrict__ localT,
    const float* __restrict__ refp, const float* __restrict__ srcp,
    float* sel_vals, int* sel_idx, float* sel_ref, float* sel_src)
{
  __shared__ int hist[2048];
  __shared__ int sh[8];
  __shared__ int eqidx[2048];
  __shared__ int selsh[LIMIT];
  __shared__ int wtot[16];
  __shared__ int bpair[2];
  const int t = threadIdx.x;
  const int lane = t & 63, wv = t >> 6;

  // phase 0: per-batch local transforms (fused former k2)
  if (t < BB){
    const float* o = &Hsr[t*15];
    float H[3][3];
#pragma unroll
    for (int c = 0; c < 3; c++)
#pragma unroll
      for (int d = 0; d < 3; d++) H[c][d] = o[c*3+d];
    float R[3][3];
    kabsch_rot_f(H, R);
    float* T = &localT[t*12];
#pragma unroll
    for (int i = 0; i < 3; i++)
#pragma unroll
      for (int j = 0; j < 3; j++) T[i*3+j] = R[i][j];
#pragma unroll
    for (int i = 0; i < 3; i++)
      T[9+i] = o[12+i] - (R[i][0]*o[9] + R[i][1]*o[10] + R[i][2]*o[11]);
  }

  // phase 1: top-2048 by 3-pass radix over positive-float keys
  int Nc = hdr[0]; if (Nc > CAND_CAP) Nc = CAND_CAP;
  if (Nc <= LIMIT){
    for (int i = t; i < LIMIT; i += 1024){
      if (i < Nc){ float v = cand_vals[i]; int ix = cand_idx[i];
                   sel_vals[i] = v; sel_idx[i] = ix; selsh[i] = ix; }
      else       { sel_vals[i] = 0.f; sel_idx[i] = 0; selsh[i] = 0; }
    }
  } else {
    // ---- parallel boundary-find lambda over hist[NB], NB in {2048, 1024} ----
    // computes: bin = largest j with suffix-sum S(j) >= need; leftover = need - S(j+1)
    auto find_boundary = [&](int NB, int need){
      int k = NB >> 10;                    // elems per thread (1 or 2)
      int base_i = t * k;
      int gv[2]; int local = 0;
      for (int e = 0; e < k; e++){ gv[e] = hist[NB-1-(base_i+e)]; local += gv[e]; }
      int incl = local;
      for (int off = 1; off < 64; off <<= 1){ int y = __shfl_up(incl, off); if (lane >= off) incl += y; }
      if (lane == 63) wtot[wv] = incl;
      __syncthreads();
      int wbase = 0;
      for (int w = 0; w < wv; w++) wbase += wtot[w];
      int P_prev = wbase + incl - local;   // prefix (reversed) exclusive
      for (int e = 0; e < k; e++){
        int P = P_prev + gv[e];
        if (P >= need && P_prev < need){   // unique thread+elem
          bpair[0] = NB-1-(base_i+e); bpair[1] = need - P_prev;
        }
        P_prev = P;
      }
      __syncthreads();
    };
    // pass 1: bits 31..21
    for (int i = t; i < 2048; i += 1024) hist[i] = 0;
    __syncthreads();
    for (int i = t; i < Nc; i += 1024)
      atomicAdd(&hist[__float_as_uint(cand_vals[i]) >> 21], 1);
    __syncthreads();
    find_boundary(2048, LIMIT);
    unsigned bin1 = (unsigned)bpair[0]; int need1 = bpair[1];
    __syncthreads();
    // pass 2: bits 20..10 within bin1
    for (int i = t; i < 2048; i += 1024) hist[i] = 0;
    __syncthreads();
    for (int i = t; i < Nc; i += 1024){
      unsigned k = __float_as_uint(cand_vals[i]);
      if ((k >> 21) == bin1) atomicAdd(&hist[(k >> 10) & 0x7FF], 1);
    }
    __syncthreads();
    find_boundary(2048, need1);
    unsigned bin2 = (unsigned)bpair[0]; int need2 = bpair[1];
    unsigned pref2 = (bin1 << 11) | bin2;
    __syncthreads();
    // pass 3: bits 9..0 within (bin1,bin2)
    for (int i = t; i < 2048; i += 1024) hist[i] = 0;
    __syncthreads();
    for (int i = t; i < Nc; i += 1024){
      unsigned k = __float_as_uint(cand_vals[i]);
      if ((k >> 10) == pref2) atomicAdd(&hist[k & 0x3FF], 1);
    }
    __syncthreads();
    find_boundary(1024, need2);
    unsigned Tkey = (pref2 << 10) | (unsigned)bpair[0];
    int needEq = bpair[1];
    if (t == 0){ sh[6] = 0; sh[7] = 0; }
    __syncthreads();
    for (int i = t; i < Nc; i += 1024){
      float v = cand_vals[i];
      unsigned k = __float_as_uint(v);
      if (k > Tkey){
        int p = atomicAdd(&sh[6], 1);
        if (p < LIMIT){ sel_vals[p] = v; sel_idx[p] = cand_idx[i]; selsh[p] = cand_idx[i]; }
      } else if (k == Tkey){
        int p = atomicAdd(&sh[7], 1);
        if (p < 2048) eqidx[p] = cand_idx[i];
      }
    }
    __syncthreads();
    if (t == 0){
      int nAbove = sh[6]; if (nAbove > LIMIT) nAbove = LIMIT;
      int neq = sh[7]; if (neq > 2048) neq = 2048;
      int take = needEq; if (take > neq) take = neq; if (nAbove + take > LIMIT) take = LIMIT - nAbove;
      // tie-break: smallest flat index first (matches jax.lax.top_k)
      for (int j = 0; j < take; j++){
        int mi = j;
        for (int l = j+1; l < neq; l++) if (eqidx[l] < eqidx[mi]) mi = l;
        int tmp = eqidx[j]; eqidx[j] = eqidx[mi]; eqidx[mi] = tmp;
        sel_vals[nAbove + j] = __uint_as_float(Tkey);
        sel_idx[nAbove + j] = eqidx[j];
        selsh[nAbove + j] = eqidx[j];
      }
      for (int j = nAbove + take; j < LIMIT; j++){ sel_vals[j] = 0.f; sel_idx[j] = 0; selsh[j] = 0; }
    }
  }
  __syncthreads();
  // phase 2: gather correspondence points (from LDS copy of indices)
  for (int p = t; p < LIMIT; p += 1024){
    int idx = selsh[p];
    int b = idx >> 14, rr = (idx >> 7) & 127, ss = idx & 127;
#pragma unroll
    for (int c = 0; c < 3; c++){
      sel_ref[p*3+c] = refp[(b*NN+rr)*3+c];
      sel_src[p*3+c] = srcp[(b*NN+ss)*3+c];
    }
  }
}

// ---------------- K45: per-batch inlier counts + last-block argmax/refine -----
__global__ __launch_bounds__(256) void k45_kernel(
    const float* __restrict__ localT, const float* __restrict__ sel_vals,
    const float* __restrict__ sel_ref, const float* __restrict__ sel_src,
    const int* __restrict__ pcount, int* counts, int* hdr, float* out)
{
  __shared__ int ired[4];
  __shared__ int lastsh;
  __shared__ double dred[4][16];
  __shared__ long long lred[4];
  __shared__ float RT[12];
  __shared__ int sbest;
  const int b = blockIdx.x, t = threadIdx.x, lane = t & 63, wv = t >> 6;

  // ---- k4 phase: count inliers for batch b ----
  {
    const float* T = &localT[b*12];
    float R00=T[0],R01=T[1],R02=T[2],R10=T[3],R11=T[4],R12=T[5],R20=T[6],R21=T[7],R22=T[8];
    float tx=T[9], ty=T[10], tz=T[11];
    int c = 0;
    for (int p = t; p < LIMIT; p += 256){
      float v = sel_vals[p];
      if (!(v > 0.f)) continue;
      float sx=sel_src[p*3], sy=sel_src[p*3+1], sz=sel_src[p*3+2];
      float rx=sel_ref[p*3], ry=sel_ref[p*3+1], rz=sel_ref[p*3+2];
      float ax = R00*sx + R01*sy + R02*sz + tx;
      float ay = R10*sx + R11*sy + R12*sz + ty;
      float az = R20*sx + R21*sy + R22*sz + tz;
      float dx = rx-ax, dy = ry-ay, dz = rz-az;
      if (sqrtf(dx*dx + dy*dy + dz*dz) < 0.1f) c++;
    }
    for (int off2 = 32; off2 > 0; off2 >>= 1) c += __shfl_down(c, off2);
    if (lane == 0) ired[wv] = c;
    __syncthreads();
    if (t == 0){
      counts[b] = (pcount[b] >= 3) ? (ired[0]+ired[1]+ired[2]+ired[3]) : -1;
      __threadfence();                       // release counts[b]
      int d = atomicAdd(&hdr[6], 1);         // device-scope
      lastsh = (d == BB - 1) ? 1 : 0;
    }
    __syncthreads();
    if (!lastsh) return;
    __threadfence();                         // acquire all counts[]
  }

  // ---- k5 phase (only the last-finishing block): argmax + 5x Procrustes ----
  {
    long long key = (long long)0x8000000000000000LL;
    for (int bb = t; bb < BB; bb += 256){
      long long kk = ((long long)(counts[bb] + 2) << 32) | (long long)(511 - bb);
      if (kk > key) key = kk;
    }
    for (int off2 = 32; off2 > 0; off2 >>= 1){ long long o = __shfl_down(key, off2); if (o > key) key = o; }
    if (lane == 0) lred[wv] = key;
    __syncthreads();
    if (t == 0){
      long long m = lred[0];
#pragma unroll
      for (int w = 1; w < 4; w++) if (lred[w] > m) m = lred[w];
      sbest = 511 - (int)(m & 0xFFFFFFFFLL);
    }
    __syncthreads();
    if (t < 12) RT[t] = localT[sbest*12 + t];
    __syncthreads();

    for (int iter = 0; iter < 5; iter++){
      float R00=RT[0],R01=RT[1],R02=RT[2];
      float R10=RT[3],R11=RT[4],R12=RT[5];
      float R20=RT[6],R21=RT[7],R22=RT[8];
      float tx=RT[9], ty=RT[10], tz=RT[11];
      double a[16];
#pragma unroll
      for (int k = 0; k < 16; k++) a[k] = 0.0;
      for (int p = t; p < LIMIT; p += 256){
        float v = sel_vals[p];
        if (!(v > 0.f)) continue;
        float sx=sel_src[p*3], sy=sel_src[p*3+1], sz=sel_src[p*3+2];
        float rx=sel_ref[p*3], ry=sel_ref[p*3+1], rz=sel_ref[p*3+2];
        float ax = R00*sx + R01*sy + R02*sz + tx;
        float ay = R10*sx + R11*sy + R12*sz + ty;
        float az = R20*sx + R21*sy + R22*sz + tz;
        float dx = rx-ax, dy = ry-ay, dz = rz-az;
        if (sqrtf(dx*dx + dy*dy + dz*dz) < 0.1f){
          double w = (double)v;
          a[0] += w;
          a[1] += w*sx; a[2] += w*sy; a[3] += w*sz;
          a[4] += w*rx; a[5] += w*ry; a[6] += w*rz;
          a[7]  += w*sx*rx; a[8]  += w*sx*ry; a[9]  += w*sx*rz;
          a[10] += w*sy*rx; a[11] += w*sy*ry; a[12] += w*sy*rz;
          a[13] += w*sz*rx; a[14] += w*sz*ry; a[15] += w*sz*rz;
        }
      }
#pragma unroll
      for (int k = 0; k < 16; k++){
        double v = a[k];
        for (int off2 = 32; off2 > 0; off2 >>= 1) v += __shfl_down(v, off2);
        if (lane == 0) dred[wv][k] = v;
      }
      __syncthreads();
      if (t == 0){
        double tot[16];
#pragma unroll
        for (int k = 0; k < 16; k++) tot[k] = dred[0][k]+dred[1][k]+dred[2][k]+dred[3][k];
        double W = tot[0], denom = W + 1e-5;
        double inv = 1.0 / denom;
        double s = W * inv;
        double scv[3] = { tot[1]*inv, tot[2]*inv, tot[3]*inv };
        double rcv[3] = { tot[4]*inv, tot[5]*inv, tot[6]*inv };
        float H[3][3];
#pragma unroll
        for (int c = 0; c < 3; c++)
#pragma unroll
          for (int d = 0; d < 3; d++)
            H[c][d] = (float)(tot[7 + c*3 + d]*inv - (2.0 - s)*scv[c]*rcv[d]);
        float R[3][3];
        kabsch_rot_f(H, R);
#pragma unroll
        for (int i = 0; i < 3; i++)
#pragma unroll
          for (int j = 0; j < 3; j++) RT[i*3+j] = R[i][j];
#pragma unroll
        for (int i = 0; i < 3; i++)
          RT[9+i] = (float)(rcv[i] - ((double)R[i][0]*scv[0] + (double)R[i][1]*scv[1] + (double)R[i][2]*scv[2]));
      }
      __syncthreads();
    }
    if (t == 0){
      out[0]=RT[0];  out[1]=RT[1];  out[2]=RT[2];  out[3]=RT[9];
      out[4]=RT[3];  out[5]=RT[4];  out[6]=RT[5];  out[7]=RT[10];
      out[8]=RT[6];  out[9]=RT[7];  out[10]=RT[8]; out[11]=RT[11];
      out[12]=0.f; out[13]=0.f; out[14]=0.f; out[15]=1.f;
    }
  }
}

// ---------------- host launcher -----------------------------------------------
extern "C" void kernel_launch(void* const* d_in, const int* in_sizes, int n_in,
                              void* d_out, int out_size, void* d_ws, size_t ws_size,
                              hipStream_t stream){
  const float* score = (const float*)d_in[0];
  const float* refp  = (const float*)d_in[1];
  const float* srcp  = (const float*)d_in[2];
  const void*  rmask = d_in[3];
  const void*  smask = d_in[4];

  char* ws = (char*)d_ws;
  size_t off = 0;
  int* hdr = (int*)(ws + off);            off += 256;
  float* cand_vals = (float*)(ws + off);  off += (size_t)CAND_CAP*4;
  int* cand_idx = (int*)(ws + off);       off += (size_t)CAND_CAP*4;
  float* Hsr = (float*)(ws + off);        off += (size_t)BB*15*4;
  int* pcount = (int*)(ws + off);         off += (size_t)BB*4;
  float* localT = (float*)(ws + off);     off += (size_t)BB*12*4;
  float* sel_vals = (float*)(ws + off);   off += (size_t)LIMIT*4;
  int* sel_idx = (int*)(ws + off);        off += (size_t)LIMIT*4;
  float* sel_ref = (float*)(ws + off);    off += (size_t)LIMIT*3*4;
  float* sel_src = (float*)(ws + off);    off += (size_t)LIMIT*3*4;
  int* counts = (int*)(ws + off);         off += (size_t)BB*4;

  hipMemsetAsync(ws, 0, 256, stream);
  hipLaunchKernelGGL(k1_kernel, dim3(BB), dim3(512), 0, stream,
                     score, refp, srcp, rmask, smask, hdr, cand_vals, cand_idx, Hsr, pcount);
  hipLaunchKernelGGL(k3_kernel, dim3(1), dim3(1024), 0, stream,
                     hdr, cand_vals, cand_idx, Hsr, localT, refp, srcp,
                     sel_vals, sel_idx, sel_ref, sel_src);
  hipLaunchKernelGGL(k45_kernel, dim3(BB), dim3(256), 0, stream,
                     localT, sel_vals, sel_ref, sel_src, pcount, counts, hdr, (float*)d_out);
}

// Round 7
// 357.070 us; speedup vs baseline: 1.2833x; 1.0041x over previous
//
#include <hip/hip_runtime.h>
#include <math.h>

#define BB 512
#define NN 128
#define CAND_CAP (512*384)
#define LIMIT 2048

// ---------------- mask decode (int32 / byte / float32 robustness) -------------
__device__ inline bool read_mask(const void* p, int i, int mode){
  if (mode == 0) return ((const int*)p)[i] != 0;
  if (mode == 1) return ((const unsigned char*)p)[i] != 0;
  return ((const float*)p)[i] != 0.0f;
}

__device__ inline float fast_rcp(float x){ return __builtin_amdgcn_rcpf(x); }
__device__ inline float fast_rsq(float x){ return __builtin_amdgcn_rsqf(x); }

__device__ inline void top3_update(float v, float& a1, float& a2, float& a3){
  if (v > a1){ a3=a2; a2=a1; a1=v; }
  else if (v > a2){ a3=a2; a2=v; }
  else if (v > a3){ a3=v; }
}

// ---------------- fp32 Kabsch, SCALAR-ONLY interface --------------------------
// R5/R6 array versions spilled to scratch (VGPR=28/32, ~146us serial latency):
// array-typed function params defeat SROA. This version has NO arrays at all —
// 9 scalars in, 9 scalar refs out, S kept as 6 scalars, V as 9. Forceinlined.
__device__ __forceinline__ void kabsch9(
    float h00, float h01, float h02,
    float h10, float h11, float h12,
    float h20, float h21, float h22,
    float& r00, float& r01, float& r02,
    float& r10, float& r11, float& r12,
    float& r20, float& r21, float& r22)
{
  // S = H^T H (symmetric, 6 scalars)
  float s00 = h00*h00 + h10*h10 + h20*h20;
  float s01 = h00*h01 + h10*h11 + h20*h21;
  float s02 = h00*h02 + h10*h12 + h20*h22;
  float s11 = h01*h01 + h11*h11 + h21*h21;
  float s12 = h01*h02 + h11*h12 + h21*h22;
  float s22 = h02*h02 + h12*h12 + h22*h22;
  float v00=1.f,v01=0.f,v02=0.f, v10=0.f,v11=1.f,v12=0.f, v20=0.f,v21=0.f,v22=1.f;
  for (int sweep = 0; sweep < 10; sweep++){
    float off  = s01*s01 + s02*s02 + s12*s12;
    float base = s00*s00 + s11*s11 + s22*s22;
    if (off <= base*1e-14f + 1e-36f) break;
    // rotation (0,1)
    if (fabsf(s01) > 1e-30f){
      float tau = (s11 - s00) * fast_rcp(2.f*s01);
      float tt  = (tau >= 0.f ? 1.f : -1.f) * fast_rcp(fabsf(tau) + sqrtf(1.f + tau*tau));
      float c = fast_rsq(1.f + tt*tt), s = tt*c;
      float n00 = c*c*s00 - 2.f*c*s*s01 + s*s*s11;
      float n11 = s*s*s00 + 2.f*c*s*s01 + c*c*s11;
      float n02 = c*s02 - s*s12;
      float n12 = s*s02 + c*s12;
      s00=n00; s11=n11; s01=0.f; s02=n02; s12=n12;
      float a,b;
      a=v00; b=v01; v00=c*a-s*b; v01=s*a+c*b;
      a=v10; b=v11; v10=c*a-s*b; v11=s*a+c*b;
      a=v20; b=v21; v20=c*a-s*b; v21=s*a+c*b;
    }
    // rotation (0,2)
    if (fabsf(s02) > 1e-30f){
      float tau = (s22 - s00) * fast_rcp(2.f*s02);
      float tt  = (tau >= 0.f ? 1.f : -1.f) * fast_rcp(fabsf(tau) + sqrtf(1.f + tau*tau));
      float c = fast_rsq(1.f + tt*tt), s = tt*c;
      float n00 = c*c*s00 - 2.f*c*s*s02 + s*s*s22;
      float n22 = s*s*s00 + 2.f*c*s*s02 + c*c*s22;
      float n01 = c*s01 - s*s12;
      float n12 = s*s01 + c*s12;
      s00=n00; s22=n22; s02=0.f; s01=n01; s12=n12;
      float a,b;
      a=v00; b=v02; v00=c*a-s*b; v02=s*a+c*b;
      a=v10; b=v12; v10=c*a-s*b; v12=s*a+c*b;
      a=v20; b=v22; v20=c*a-s*b; v22=s*a+c*b;
    }
    // rotation (1,2)
    if (fabsf(s12) > 1e-30f){
      float tau = (s22 - s11) * fast_rcp(2.f*s12);
      float tt  = (tau >= 0.f ? 1.f : -1.f) * fast_rcp(fabsf(tau) + sqrtf(1.f + tau*tau));
      float c = fast_rsq(1.f + tt*tt), s = tt*c;
      float n11 = c*c*s11 - 2.f*c*s*s12 + s*s*s22;
      float n22 = s*s*s11 + 2.f*c*s*s12 + c*c*s22;
      float n01 = c*s01 - s*s02;
      float n02 = s*s01 + c*s02;
      s11=n11; s22=n22; s12=0.f; s01=n01; s02=n02;
      float a,b;
      a=v01; b=v02; v01=c*a-s*b; v02=s*a+c*b;
      a=v11; b=v12; v11=c*a-s*b; v12=s*a+c*b;
      a=v21; b=v22; v21=c*a-s*b; v22=s*a+c*b;
    }
  }
  // eigen columns as scalars; sort descending via compare-swaps
  float l0=s00, l1=s11, l2=s22;
  float a0=v00, a1=v10, a2=v20;   // column 0
  float b0=v01, b1=v11, b2=v21;   // column 1
  float c0=v02, c1=v12, c2=v22;   // column 2
  if (l0 < l1){ float x; x=l0;l0=l1;l1=x; x=a0;a0=b0;b0=x; x=a1;a1=b1;b1=x; x=a2;a2=b2;b2=x; }
  if (l0 < l2){ float x; x=l0;l0=l2;l2=x; x=a0;a0=c0;c0=x; x=a1;a1=c1;c1=x; x=a2;a2=c2;c2=x; }
  if (l1 < l2){ float x; x=l1;l1=l2;l2=x; x=b0;b0=c0;c0=x; x=b1;b1=c1;c1=x; x=b2;b2=c2;c2=x; }
  float sig0 = sqrtf(fmaxf(l0, 0.f));
  if (!(sig0 > 1e-12f)){
    r00=1.f; r01=0.f; r02=0.f; r10=0.f; r11=1.f; r12=0.f; r20=0.f; r21=0.f; r22=1.f;
    return;
  }
  // u0 = normalize(H a)
  float u0x = h00*a0 + h01*a1 + h02*a2;
  float u0y = h10*a0 + h11*a1 + h12*a2;
  float u0z = h20*a0 + h21*a1 + h22*a2;
  float in0 = fast_rsq(u0x*u0x + u0y*u0y + u0z*u0z);
  u0x *= in0; u0y *= in0; u0z *= in0;
  // u1 = orthonormalize(H b) against u0
  float u1x = h00*b0 + h01*b1 + h02*b2;
  float u1y = h10*b0 + h11*b1 + h12*b2;
  float u1z = h20*b0 + h21*b1 + h22*b2;
  float dp = u1x*u0x + u1y*u0y + u1z*u0z;
  u1x -= dp*u0x; u1y -= dp*u0y; u1z -= dp*u0z;
  float d1 = u1x*u1x + u1y*u1y + u1z*u1z;
  if (sqrtf(d1) > sig0*1e-5f){
    float in1 = fast_rsq(d1);
    u1x *= in1; u1y *= in1; u1z *= in1;
  } else {
    float au0 = fabsf(u0x), au1 = fabsf(u0y), au2 = fabsf(u0z);
    float e0 = 0.f, e1 = 0.f, e2 = 0.f;
    if (au0 <= au1 && au0 <= au2) e0 = 1.f; else if (au1 <= au2) e1 = 1.f; else e2 = 1.f;
    float d2 = e0*u0x + e1*u0y + e2*u0z;
    u1x = e0 - d2*u0x; u1y = e1 - d2*u0y; u1z = e2 - d2*u0z;
    float nn = fast_rsq(u1x*u1x + u1y*u1y + u1z*u1z);
    u1x *= nn; u1y *= nn; u1z *= nn;
  }
  float u2x = u0y*u1z - u0z*u1y;
  float u2y = u0z*u1x - u0x*u1z;
  float u2z = u0x*u1y - u0y*u1x;
  // d = sign(det V)   (det U = +1 by construction)
  float cxv = b1*c2 - b2*c1;
  float cyv = b2*c0 - b0*c2;
  float czv = b0*c1 - b1*c0;
  float detV = a0*cxv + a1*cyv + a2*czv;
  float dd = (detV >= 0.f) ? 1.f : -1.f;
  float w2x = dd*u2x, w2y = dd*u2y, w2z = dd*u2z;
  r00=a0*u0x + b0*u1x + c0*w2x;  r01=a0*u0y + b0*u1y + c0*w2y;  r02=a0*u0z + b0*u1z + c0*w2z;
  r10=a1*u0x + b1*u1x + c1*w2x;  r11=a1*u0y + b1*u1y + c1*w2y;  r12=a1*u0z + b1*u1z + c1*w2z;
  r20=a2*u0x + b2*u1x + c2*w2x;  r21=a2*u0y + b2*u1y + c2*w2y;  r22=a2*u0z + b2*u1z + c2*w2z;
}

// ---------------- K1: raw-score mutual top-3, sparse exp, stats, candidates ---
// 512 threads: thread t -> row r = t&127, quarter q = t>>7 (32 cols/rows each)
__global__ __launch_bounds__(512, 4) void k1_kernel(
    const float* __restrict__ score, const float* __restrict__ refp,
    const float* __restrict__ srcp, const void* __restrict__ rmaskp,
    const void* __restrict__ smaskp, int* hdr, float* cand_vals, int* cand_idx,
    float* Hsr, int* pcount)
{
  __shared__ float tile[NN*NN];        // 64 KB raw-score tile
  __shared__ float part[4][NN][3];     // reused: col partials, then row partials
  __shared__ float c3sh[NN], r3sh[NN];
  __shared__ unsigned char smk[NN], rmk[NN];
  __shared__ float srcsh[NN*3];
  __shared__ float red[8][17];
  __shared__ int wsum[8];
  __shared__ int basesh;
  __shared__ int smode;
  const int b = blockIdx.x, t = threadIdx.x;
  const int r = t & 127, q = t >> 7;
  const int lane = t & 63, wv = t >> 6;

  // mode detect (wave 0): int32 0/1, byte, or float 0/1.0
  if (t < 64){
    unsigned v = ((const unsigned*)rmaskp)[t];
    bool n01 = !(v == 0u || v == 1u);
    bool nf  = !(v == 0u || v == 0x3F800000u);
    unsigned long long b01 = __ballot(n01), bf = __ballot(nf);
    if (t == 0) smode = (b01 == 0ull) ? 0 : ((bf == 0ull) ? 2 : 1);
  }

  // coalesced raw load (no exp!)
  {
    const float4* s4 = (const float4*)(score + (size_t)b*NN*NN);
    float4* t4 = (float4*)tile;
    for (int j = t; j < NN*NN/4; j += 512) t4[j] = s4[j];
  }
  __syncthreads();   // tile + smode ready

  if (t < NN){
    int mode = smode;
    smk[t] = read_mask(smaskp, b*NN + t, mode) ? 1 : 0;
    rmk[t] = read_mask(rmaskp, b*NN + t, mode) ? 1 : 0;
    srcsh[t*3+0] = srcp[(b*NN+t)*3+0];
    srcsh[t*3+1] = srcp[(b*NN+t)*3+1];
    srcsh[t*3+2] = srcp[(b*NN+t)*3+2];
  }
  // column partial top-3: column c=r, rows [q*32, q*32+32)
  {
    float a1=-1e30f, a2=-1e30f, a3=-1e30f;
    for (int i = 0; i < 32; i++){
      float v = tile[(q*32 + i)*NN + r];
      top3_update(v, a1, a2, a3);
    }
    part[q][r][0]=a1; part[q][r][1]=a2; part[q][r][2]=a3;
  }
  __syncthreads();
  if (t < NN){
    float m1=-1e30f, m2=-1e30f, m3=-1e30f;
#pragma unroll
    for (int qq = 0; qq < 4; qq++)
#pragma unroll
      for (int j = 0; j < 3; j++) top3_update(part[qq][t][j], m1, m2, m3);
    c3sh[t] = m3;
  }
  __syncthreads();
  // row partial top-3: row r, cols q*32 + ((r+i)&31)  (rotation: 2-way banks, free)
  {
    float a1=-1e30f, a2=-1e30f, a3=-1e30f;
    for (int i = 0; i < 32; i++){
      int c = q*32 + ((r + i) & 31);
      top3_update(tile[r*NN + c], a1, a2, a3);
    }
    part[q][r][0]=a1; part[q][r][1]=a2; part[q][r][2]=a3;
  }
  __syncthreads();
  if (t < NN){
    float m1=-1e30f, m2=-1e30f, m3=-1e30f;
#pragma unroll
    for (int qq = 0; qq < 4; qq++)
#pragma unroll
      for (int j = 0; j < 3; j++) top3_update(part[qq][t][j], m1, m2, m3);
    r3sh[t] = m3;
  }
  __syncthreads();

  // masked pass: mutual top-3 on RAW (exp monotone), expf only at survivors
  float wr = 0.f, p0 = 0.f, p1 = 0.f, p2 = 0.f, cntf = 0.f;
  float kv[3]; int km[3]; int cnt = 0;
  const float r3 = r3sh[r];
  const bool rmv = rmk[r] != 0;
  const float rx = refp[(b*NN+r)*3+0], ry = refp[(b*NN+r)*3+1], rz = refp[(b*NN+r)*3+2];
  for (int i = 0; i < 32; i++){
    int c = q*32 + ((r + i) & 31);
    float v = tile[r*NN + c];
    if (rmv && smk[c] && v >= r3 && v >= c3sh[c]){
      float e = expf(v);
      if (e > 0.05f){
        cntf += 1.f; wr += e;
        p0 += e*srcsh[c*3+0]; p1 += e*srcsh[c*3+1]; p2 += e*srcsh[c*3+2];
        if (cnt < 3){ kv[cnt] = e; km[cnt] = c; cnt++; }
      }
    }
  }
  // block-wide exclusive scan of cnt -> single atomic per block
  int x = cnt;
  for (int off2 = 1; off2 < 64; off2 <<= 1){ int y = __shfl_up(x, off2); if (lane >= off2) x += y; }
  if (lane == 63) wsum[wv] = x;
  __syncthreads();
  if (t == 0){
    int s2 = 0;
#pragma unroll
    for (int w = 0; w < 8; w++) s2 += wsum[w];
    basesh = atomicAdd(&hdr[0], s2);
  }
  __syncthreads();
  {
    int base = basesh + (x - cnt);
    for (int w = 0; w < wv; w++) base += wsum[w];
    for (int j = 0; j < cnt; j++){
      int pos = base + j;
      if (pos < CAND_CAP){ cand_vals[pos] = kv[j]; cand_idx[pos] = (b<<14)|(r<<7)|km[j]; }
    }
  }
  // 17-value block reduction
  float qv[17];
  qv[0]=cntf; qv[1]=wr;
  qv[2]=wr*rx; qv[3]=wr*ry; qv[4]=wr*rz;     // rc numerator
  qv[5]=p0; qv[6]=p1; qv[7]=p2;              // sc numerator (= sum e*src)
  qv[8]=p0*rx;  qv[9]=p0*ry;  qv[10]=p0*rz;  // M^[c][d] = sum e*src_c*ref_d
  qv[11]=p1*rx; qv[12]=p1*ry; qv[13]=p1*rz;
  qv[14]=p2*rx; qv[15]=p2*ry; qv[16]=p2*rz;
#pragma unroll
  for (int k = 0; k < 17; k++){
    float v = qv[k];
    for (int off2 = 32; off2 > 0; off2 >>= 1) v += __shfl_down(v, off2);
    if (lane == 0) red[wv][k] = v;
  }
  __syncthreads();
  if (t == 0){
    float tot[17];
#pragma unroll
    for (int k = 0; k < 17; k++){
      float s2 = 0.f;
#pragma unroll
      for (int w = 0; w < 8; w++) s2 += red[w][k];
      tot[k] = s2;
    }
    float Wm = tot[1];
    float denom = Wm + 1e-5f;
    float idenom = 1.f / denom;
    float s = Wm * idenom;
    float rcv[3] = { tot[2]*idenom, tot[3]*idenom, tot[4]*idenom };
    float scv[3] = { tot[5]*idenom, tot[6]*idenom, tot[7]*idenom };
    float* o = &Hsr[b*15];
#pragma unroll
    for (int c = 0; c < 3; c++)
#pragma unroll
      for (int d = 0; d < 3; d++)
        o[c*3+d] = tot[8 + c*3 + d]*idenom - (2.f - s)*scv[c]*rcv[d];
    o[9]=scv[0]; o[10]=scv[1]; o[11]=scv[2];
    o[12]=rcv[0]; o[13]=rcv[1]; o[14]=rcv[2];
    pcount[b] = (int)(tot[0] + 0.5f);
  }
}

// ---------------- K3: single-block top-2048 + gather (no Kabsch here) ---------
__global__ __launch_bounds__(1024) void k3_kernel(
    const int* hdr, const float* __restrict__ cand_vals, const int* __restrict__ cand_idx,
    const float* __restrict__ refp, const float* __restrict__ srcp,
    float* sel_vals, int* sel_idx, float* sel_ref, float* sel_src)
{
  __shared__ int hist[2048];
  __shared__ int sh[8];
  __shared__ int eqidx[2048];
  __shared__ int selsh[LIMIT];
  __shared__ int wtot[16];
  __shared__ int bpair[2];
  const int t = threadIdx.x;
  const int lane = t & 63, wv = t >> 6;

  // phase 1: top-2048 by 3-pass radix over positive-float keys
  int Nc = hdr[0]; if (Nc > CAND_CAP) Nc = CAND_CAP;
  if (Nc <= LIMIT){
    for (int i = t; i < LIMIT; i += 1024){
      if (i < Nc){ float v = cand_vals[i]; int ix = cand_idx[i];
                   sel_vals[i] = v; sel_idx[i] = ix; selsh[i] = ix; }
      else       { sel_vals[i] = 0.f; sel_idx[i] = 0; selsh[i] = 0; }
    }
  } else {
    // ---- parallel boundary-find over hist[NB], NB in {2048, 1024} ----
    // computes: bin = largest j with suffix-sum S(j) >= need; leftover = need - S(j+1)
    auto find_boundary = [&](int NB, int need){
      int k = NB >> 10;                    // elems per thread (1 or 2)
      int base_i = t * k;
      int gv[2]; int local = 0;
      for (int e = 0; e < k; e++){ gv[e] = hist[NB-1-(base_i+e)]; local += gv[e]; }
      int incl = local;
      for (int off = 1; off < 64; off <<= 1){ int y = __shfl_up(incl, off); if (lane >= off) incl += y; }
      if (lane == 63) wtot[wv] = incl;
      __syncthreads();
      int wbase = 0;
      for (int w = 0; w < wv; w++) wbase += wtot[w];
      int P_prev = wbase + incl - local;   // prefix (reversed) exclusive
      for (int e = 0; e < k; e++){
        int P = P_prev + gv[e];
        if (P >= need && P_prev < need){   // unique thread+elem
          bpair[0] = NB-1-(base_i+e); bpair[1] = need - P_prev;
        }
        P_prev = P;
      }
      __syncthreads();
    };
    // pass 1: bits 31..21
    for (int i = t; i < 2048; i += 1024) hist[i] = 0;
    __syncthreads();
    for (int i = t; i < Nc; i += 1024)
      atomicAdd(&hist[__float_as_uint(cand_vals[i]) >> 21], 1);
    __syncthreads();
    find_boundary(2048, LIMIT);
    unsigned bin1 = (unsigned)bpair[0]; int need1 = bpair[1];
    __syncthreads();
    // pass 2: bits 20..10 within bin1
    for (int i = t; i < 2048; i += 1024) hist[i] = 0;
    __syncthreads();
    for (int i = t; i < Nc; i += 1024){
      unsigned k = __float_as_uint(cand_vals[i]);
      if ((k >> 21) == bin1) atomicAdd(&hist[(k >> 10) & 0x7FF], 1);
    }
    __syncthreads();
    find_boundary(2048, need1);
    unsigned bin2 = (unsigned)bpair[0]; int need2 = bpair[1];
    unsigned pref2 = (bin1 << 11) | bin2;
    __syncthreads();
    // pass 3: bits 9..0 within (bin1,bin2)
    for (int i = t; i < 2048; i += 1024) hist[i] = 0;
    __syncthreads();
    for (int i = t; i < Nc; i += 1024){
      unsigned k = __float_as_uint(cand_vals[i]);
      if ((k >> 10) == pref2) atomicAdd(&hist[k & 0x3FF], 1);
    }
    __syncthreads();
    find_boundary(1024, need2);
    unsigned Tkey = (pref2 << 10) | (unsigned)bpair[0];
    int needEq = bpair[1];
    if (t == 0){ sh[6] = 0; sh[7] = 0; }
    __syncthreads();
    for (int i = t; i < Nc; i += 1024){
      float v = cand_vals[i];
      unsigned k = __float_as_uint(v);
      if (k > Tkey){
        int p = atomicAdd(&sh[6], 1);
        if (p < LIMIT){ sel_vals[p] = v; sel_idx[p] = cand_idx[i]; selsh[p] = cand_idx[i]; }
      } else if (k == Tkey){
        int p = atomicAdd(&sh[7], 1);
        if (p < 2048) eqidx[p] = cand_idx[i];
      }
    }
    __syncthreads();
    if (t == 0){
      int nAbove = sh[6]; if (nAbove > LIMIT) nAbove = LIMIT;
      int neq = sh[7]; if (neq > 2048) neq = 2048;
      int take = needEq; if (take > neq) take = neq; if (nAbove + take > LIMIT) take = LIMIT - nAbove;
      // tie-break: smallest flat index first (matches jax.lax.top_k)
      for (int j = 0; j < take; j++){
        int mi = j;
        for (int l = j+1; l < neq; l++) if (eqidx[l] < eqidx[mi]) mi = l;
        int tmp = eqidx[j]; eqidx[j] = eqidx[mi]; eqidx[mi] = tmp;
        sel_vals[nAbove + j] = __uint_as_float(Tkey);
        sel_idx[nAbove + j] = eqidx[j];
        selsh[nAbove + j] = eqidx[j];
      }
      for (int j = nAbove + take; j < LIMIT; j++){ sel_vals[j] = 0.f; sel_idx[j] = 0; selsh[j] = 0; }
    }
  }
  __syncthreads();
  // phase 2: gather correspondence points (from LDS copy of indices)
  for (int p = t; p < LIMIT; p += 1024){
    int idx = selsh[p];
    int b = idx >> 14, rr = (idx >> 7) & 127, ss = idx & 127;
#pragma unroll
    for (int c = 0; c < 3; c++){
      sel_ref[p*3+c] = refp[(b*NN+rr)*3+c];
      sel_src[p*3+c] = srcp[(b*NN+ss)*3+c];
    }
  }
}

// ---------------- K45: per-block Kabsch + inlier counts + last-block refine ---
__global__ __launch_bounds__(256) void k45_kernel(
    const float* __restrict__ Hsr, float* __restrict__ localT,
    const float* __restrict__ sel_vals, const float* __restrict__ sel_ref,
    const float* __restrict__ sel_src, const int* __restrict__ pcount,
    int* counts, int* hdr, float* out)
{
  __shared__ float Tsh[12];
  __shared__ int ired[4];
  __shared__ int lastsh;
  __shared__ double dred[4][16];
  __shared__ long long lred[4];
  __shared__ float RT[12];
  __shared__ int sbest;
  const int b = blockIdx.x, t = threadIdx.x, lane = t & 63, wv = t >> 6;

  // ---- phase A: this block computes its own local transform (register Kabsch)
  if (t == 0){
    const float* o = &Hsr[b*15];
    float r00,r01,r02,r10,r11,r12,r20,r21,r22;
    kabsch9(o[0],o[1],o[2], o[3],o[4],o[5], o[6],o[7],o[8],
            r00,r01,r02,r10,r11,r12,r20,r21,r22);
    Tsh[0]=r00; Tsh[1]=r01; Tsh[2]=r02;
    Tsh[3]=r10; Tsh[4]=r11; Tsh[5]=r12;
    Tsh[6]=r20; Tsh[7]=r21; Tsh[8]=r22;
    Tsh[9]  = o[12] - (r00*o[9] + r01*o[10] + r02*o[11]);
    Tsh[10] = o[13] - (r10*o[9] + r11*o[10] + r12*o[11]);
    Tsh[11] = o[14] - (r20*o[9] + r21*o[10] + r22*o[11]);
  }
  __syncthreads();
  if (t < 12) localT[b*12 + t] = Tsh[t];

  // ---- k4 phase: count inliers for batch b ----
  {
    float R00=Tsh[0],R01=Tsh[1],R02=Tsh[2],R10=Tsh[3],R11=Tsh[4],R12=Tsh[5];
    float R20=Tsh[6],R21=Tsh[7],R22=Tsh[8];
    float tx=Tsh[9], ty=Tsh[10], tz=Tsh[11];
    int c = 0;
    for (int p = t; p < LIMIT; p += 256){
      float v = sel_vals[p];
      if (!(v > 0.f)) continue;
      float sx=sel_src[p*3], sy=sel_src[p*3+1], sz=sel_src[p*3+2];
      float rx=sel_ref[p*3], ry=sel_ref[p*3+1], rz=sel_ref[p*3+2];
      float ax = R00*sx + R01*sy + R02*sz + tx;
      float ay = R10*sx + R11*sy + R12*sz + ty;
      float az = R20*sx + R21*sy + R22*sz + tz;
      float dx = rx-ax, dy = ry-ay, dz = rz-az;
      if (sqrtf(dx*dx + dy*dy + dz*dz) < 0.1f) c++;
    }
    for (int off2 = 32; off2 > 0; off2 >>= 1) c += __shfl_down(c, off2);
    if (lane == 0) ired[wv] = c;
    __syncthreads();
    if (t == 0){
      counts[b] = (pcount[b] >= 3) ? (ired[0]+ired[1]+ired[2]+ired[3]) : -1;
      __threadfence();                       // release counts[b] + localT[b]
      int d = atomicAdd(&hdr[6], 1);         // device-scope
      lastsh = (d == BB - 1) ? 1 : 0;
    }
    __syncthreads();
    if (!lastsh) return;
    __threadfence();                         // acquire all counts[] / localT[]
  }

  // ---- k5 phase (only the last-finishing block): argmax + 5x Procrustes ----
  {
    long long key = (long long)0x8000000000000000LL;
    for (int bb = t; bb < BB; bb += 256){
      long long kk = ((long long)(counts[bb] + 2) << 32) | (long long)(511 - bb);
      if (kk > key) key = kk;
    }
    for (int off2 = 32; off2 > 0; off2 >>= 1){ long long o = __shfl_down(key, off2); if (o > key) key = o; }
    if (lane == 0) lred[wv] = key;
    __syncthreads();
    if (t == 0){
      long long m = lred[0];
#pragma unroll
      for (int w = 1; w < 4; w++) if (lred[w] > m) m = lred[w];
      sbest = 511 - (int)(m & 0xFFFFFFFFLL);
    }
    __syncthreads();
    if (t < 12) RT[t] = localT[sbest*12 + t];
    __syncthreads();

    for (int iter = 0; iter < 5; iter++){
      float R00=RT[0],R01=RT[1],R02=RT[2];
      float R10=RT[3],R11=RT[4],R12=RT[5];
      float R20=RT[6],R21=RT[7],R22=RT[8];
      float tx=RT[9], ty=RT[10], tz=RT[11];
      double a[16];
#pragma unroll
      for (int k = 0; k < 16; k++) a[k] = 0.0;
      for (int p = t; p < LIMIT; p += 256){
        float v = sel_vals[p];
        if (!(v > 0.f)) continue;
        float sx=sel_src[p*3], sy=sel_src[p*3+1], sz=sel_src[p*3+2];
        float rx=sel_ref[p*3], ry=sel_ref[p*3+1], rz=sel_ref[p*3+2];
        float ax = R00*sx + R01*sy + R02*sz + tx;
        float ay = R10*sx + R11*sy + R12*sz + ty;
        float az = R20*sx + R21*sy + R22*sz + tz;
        float dx = rx-ax, dy = ry-ay, dz = rz-az;
        if (sqrtf(dx*dx + dy*dy + dz*dz) < 0.1f){
          double w = (double)v;
          a[0] += w;
          a[1] += w*sx; a[2] += w*sy; a[3] += w*sz;
          a[4] += w*rx; a[5] += w*ry; a[6] += w*rz;
          a[7]  += w*sx*rx; a[8]  += w*sx*ry; a[9]  += w*sx*rz;
          a[10] += w*sy*rx; a[11] += w*sy*ry; a[12] += w*sy*rz;
          a[13] += w*sz*rx; a[14] += w*sz*ry; a[15] += w*sz*rz;
        }
      }
#pragma unroll
      for (int k = 0; k < 16; k++){
        double v = a[k];
        for (int off2 = 32; off2 > 0; off2 >>= 1) v += __shfl_down(v, off2);
        if (lane == 0) dred[wv][k] = v;
      }
      __syncthreads();
      if (t == 0){
        double tot[16];
#pragma unroll
        for (int k = 0; k < 16; k++) tot[k] = dred[0][k]+dred[1][k]+dred[2][k]+dred[3][k];
        double W = tot[0], denom = W + 1e-5;
        double inv = 1.0 / denom;
        double s = W * inv;
        double scv[3] = { tot[1]*inv, tot[2]*inv, tot[3]*inv };
        double rcv[3] = { tot[4]*inv, tot[5]*inv, tot[6]*inv };
        float h00 = (float)(tot[7]*inv  - (2.0 - s)*scv[0]*rcv[0]);
        float h01 = (float)(tot[8]*inv  - (2.0 - s)*scv[0]*rcv[1]);
        float h02 = (float)(tot[9]*inv  - (2.0 - s)*scv[0]*rcv[2]);
        float h10 = (float)(tot[10]*inv - (2.0 - s)*scv[1]*rcv[0]);
        float h11 = (float)(tot[11]*inv - (2.0 - s)*scv[1]*rcv[1]);
        float h12 = (float)(tot[12]*inv - (2.0 - s)*scv[1]*rcv[2]);
        float h20 = (float)(tot[13]*inv - (2.0 - s)*scv[2]*rcv[0]);
        float h21 = (float)(tot[14]*inv - (2.0 - s)*scv[2]*rcv[1]);
        float h22 = (float)(tot[15]*inv - (2.0 - s)*scv[2]*rcv[2]);
        float r00,r01,r02,r10,r11,r12,r20,r21,r22;
        kabsch9(h00,h01,h02,h10,h11,h12,h20,h21,h22,
                r00,r01,r02,r10,r11,r12,r20,r21,r22);
        RT[0]=r00; RT[1]=r01; RT[2]=r02;
        RT[3]=r10; RT[4]=r11; RT[5]=r12;
        RT[6]=r20; RT[7]=r21; RT[8]=r22;
        RT[9]  = (float)(rcv[0] - ((double)r00*scv[0] + (double)r01*scv[1] + (double)r02*scv[2]));
        RT[10] = (float)(rcv[1] - ((double)r10*scv[0] + (double)r11*scv[1] + (double)r12*scv[2]));
        RT[11] = (float)(rcv[2] - ((double)r20*scv[0] + (double)r21*scv[1] + (double)r22*scv[2]));
      }
      __syncthreads();
    }
    if (t == 0){
      out[0]=RT[0];  out[1]=RT[1];  out[2]=RT[2];  out[3]=RT[9];
      out[4]=RT[3];  out[5]=RT[4];  out[6]=RT[5];  out[7]=RT[10];
      out[8]=RT[6];  out[9]=RT[7];  out[10]=RT[8]; out[11]=RT[11];
      out[12]=0.f; out[13]=0.f; out[14]=0.f; out[15]=1.f;
    }
  }
}

// ---------------- host launcher -----------------------------------------------
extern "C" void kernel_launch(void* const* d_in, const int* in_sizes, int n_in,
                              void* d_out, int out_size, void* d_ws, size_t ws_size,
                              hipStream_t stream){
  const float* score = (const float*)d_in[0];
  const float* refp  = (const float*)d_in[1];
  const float* srcp  = (const float*)d_in[2];
  const void*  rmask = d_in[3];
  const void*  smask = d_in[4];

  char* ws = (char*)d_ws;
  size_t off = 0;
  int* hdr = (int*)(ws + off);            off += 256;
  float* cand_vals = (float*)(ws + off);  off += (size_t)CAND_CAP*4;
  int* cand_idx = (int*)(ws + off);       off += (size_t)CAND_CAP*4;
  float* Hsr = (float*)(ws + off);        off += (size_t)BB*15*4;
  int* pcount = (int*)(ws + off);         off += (size_t)BB*4;
  float* localT = (float*)(ws + off);     off += (size_t)BB*12*4;
  float* sel_vals = (float*)(ws + off);   off += (size_t)LIMIT*4;
  int* sel_idx = (int*)(ws + off);        off += (size_t)LIMIT*4;
  float* sel_ref = (float*)(ws + off);    off += (size_t)LIMIT*3*4;
  float* sel_src = (float*)(ws + off);    off += (size_t)LIMIT*3*4;
  int* counts = (int*)(ws + off);         off += (size_t)BB*4;

  hipMemsetAsync(ws, 0, 256, stream);
  hipLaunchKernelGGL(k1_kernel, dim3(BB), dim3(512), 0, stream,
                     score, refp, srcp, rmask, smask, hdr, cand_vals, cand_idx, Hsr, pcount);
  hipLaunchKernelGGL(k3_kernel, dim3(1), dim3(1024), 0, stream,
                     hdr, cand_vals, cand_idx, refp, srcp,
                     sel_vals, sel_idx, sel_ref, sel_src);
  hipLaunchKernelGGL(k45_kernel, dim3(BB), dim3(256), 0, stream,
                     Hsr, localT, sel_vals, sel_ref, sel_src, pcount, counts, hdr, (float*)d_out);
}

// Round 8
// 257.493 us; speedup vs baseline: 1.7796x; 1.3867x over previous
//
#include <hip/hip_runtime.h>
#include <math.h>

#define BB 512
#define NN 128
#define CAND_CAP (512*384)
#define LIMIT 2048
#define EQCAP 16384
#define NBIN1 4096

// ---------------- mask decode (int32 / byte / float32 robustness) -------------
__device__ inline bool read_mask(const void* p, int i, int mode){
  if (mode == 0) return ((const int*)p)[i] != 0;
  if (mode == 1) return ((const unsigned char*)p)[i] != 0;
  return ((const float*)p)[i] != 0.0f;
}

__device__ inline float fast_rcp(float x){ return __builtin_amdgcn_rcpf(x); }
__device__ inline float fast_rsq(float x){ return __builtin_amdgcn_rsqf(x); }

__device__ inline void top3_update(float v, float& a1, float& a2, float& a3){
  if (v > a1){ a3=a2; a2=a1; a1=v; }
  else if (v > a2){ a3=a2; a2=v; }
  else if (v > a3){ a3=v; }
}

// ---------------- fp32 Kabsch, SCALAR-ONLY interface --------------------------
// Array-typed params defeat SROA (R5/R6: VGPR=28/32, scratch chains). This
// version: 9 scalars in, 9 scalar refs out, no arrays anywhere. Forceinlined.
__device__ __forceinline__ void kabsch9(
    float h00, float h01, float h02,
    float h10, float h11, float h12,
    float h20, float h21, float h22,
    float& r00, float& r01, float& r02,
    float& r10, float& r11, float& r12,
    float& r20, float& r21, float& r22)
{
  float s00 = h00*h00 + h10*h10 + h20*h20;
  float s01 = h00*h01 + h10*h11 + h20*h21;
  float s02 = h00*h02 + h10*h12 + h20*h22;
  float s11 = h01*h01 + h11*h11 + h21*h21;
  float s12 = h01*h02 + h11*h12 + h21*h22;
  float s22 = h02*h02 + h12*h12 + h22*h22;
  float v00=1.f,v01=0.f,v02=0.f, v10=0.f,v11=1.f,v12=0.f, v20=0.f,v21=0.f,v22=1.f;
  for (int sweep = 0; sweep < 10; sweep++){
    float off  = s01*s01 + s02*s02 + s12*s12;
    float base = s00*s00 + s11*s11 + s22*s22;
    if (off <= base*1e-14f + 1e-36f) break;
    if (fabsf(s01) > 1e-30f){
      float tau = (s11 - s00) * fast_rcp(2.f*s01);
      float tt  = (tau >= 0.f ? 1.f : -1.f) * fast_rcp(fabsf(tau) + sqrtf(1.f + tau*tau));
      float c = fast_rsq(1.f + tt*tt), s = tt*c;
      float n00 = c*c*s00 - 2.f*c*s*s01 + s*s*s11;
      float n11 = s*s*s00 + 2.f*c*s*s01 + c*c*s11;
      float n02 = c*s02 - s*s12;
      float n12 = s*s02 + c*s12;
      s00=n00; s11=n11; s01=0.f; s02=n02; s12=n12;
      float a,b;
      a=v00; b=v01; v00=c*a-s*b; v01=s*a+c*b;
      a=v10; b=v11; v10=c*a-s*b; v11=s*a+c*b;
      a=v20; b=v21; v20=c*a-s*b; v21=s*a+c*b;
    }
    if (fabsf(s02) > 1e-30f){
      float tau = (s22 - s00) * fast_rcp(2.f*s02);
      float tt  = (tau >= 0.f ? 1.f : -1.f) * fast_rcp(fabsf(tau) + sqrtf(1.f + tau*tau));
      float c = fast_rsq(1.f + tt*tt), s = tt*c;
      float n00 = c*c*s00 - 2.f*c*s*s02 + s*s*s22;
      float n22 = s*s*s00 + 2.f*c*s*s02 + c*c*s22;
      float n01 = c*s01 - s*s12;
      float n12 = s*s01 + c*s12;
      s00=n00; s22=n22; s02=0.f; s01=n01; s12=n12;
      float a,b;
      a=v00; b=v02; v00=c*a-s*b; v02=s*a+c*b;
      a=v10; b=v12; v10=c*a-s*b; v12=s*a+c*b;
      a=v20; b=v22; v20=c*a-s*b; v22=s*a+c*b;
    }
    if (fabsf(s12) > 1e-30f){
      float tau = (s22 - s11) * fast_rcp(2.f*s12);
      float tt  = (tau >= 0.f ? 1.f : -1.f) * fast_rcp(fabsf(tau) + sqrtf(1.f + tau*tau));
      float c = fast_rsq(1.f + tt*tt), s = tt*c;
      float n11 = c*c*s11 - 2.f*c*s*s12 + s*s*s22;
      float n22 = s*s*s11 + 2.f*c*s*s12 + c*c*s22;
      float n01 = c*s01 - s*s02;
      float n02 = s*s01 + c*s02;
      s11=n11; s22=n22; s12=0.f; s01=n01; s02=n02;
      float a,b;
      a=v01; b=v02; v01=c*a-s*b; v02=s*a+c*b;
      a=v11; b=v12; v11=c*a-s*b; v12=s*a+c*b;
      a=v21; b=v22; v21=c*a-s*b; v22=s*a+c*b;
    }
  }
  float l0=s00, l1=s11, l2=s22;
  float a0=v00, a1=v10, a2=v20;
  float b0=v01, b1=v11, b2=v21;
  float c0=v02, c1=v12, c2=v22;
  if (l0 < l1){ float x; x=l0;l0=l1;l1=x; x=a0;a0=b0;b0=x; x=a1;a1=b1;b1=x; x=a2;a2=b2;b2=x; }
  if (l0 < l2){ float x; x=l0;l0=l2;l2=x; x=a0;a0=c0;c0=x; x=a1;a1=c1;c1=x; x=a2;a2=c2;c2=x; }
  if (l1 < l2){ float x; x=l1;l1=l2;l2=x; x=b0;b0=c0;c0=x; x=b1;b1=c1;c1=x; x=b2;b2=c2;c2=x; }
  float sig0 = sqrtf(fmaxf(l0, 0.f));
  if (!(sig0 > 1e-12f)){
    r00=1.f; r01=0.f; r02=0.f; r10=0.f; r11=1.f; r12=0.f; r20=0.f; r21=0.f; r22=1.f;
    return;
  }
  float u0x = h00*a0 + h01*a1 + h02*a2;
  float u0y = h10*a0 + h11*a1 + h12*a2;
  float u0z = h20*a0 + h21*a1 + h22*a2;
  float in0 = fast_rsq(u0x*u0x + u0y*u0y + u0z*u0z);
  u0x *= in0; u0y *= in0; u0z *= in0;
  float u1x = h00*b0 + h01*b1 + h02*b2;
  float u1y = h10*b0 + h11*b1 + h12*b2;
  float u1z = h20*b0 + h21*b1 + h22*b2;
  float dp = u1x*u0x + u1y*u0y + u1z*u0z;
  u1x -= dp*u0x; u1y -= dp*u0y; u1z -= dp*u0z;
  float d1 = u1x*u1x + u1y*u1y + u1z*u1z;
  if (sqrtf(d1) > sig0*1e-5f){
    float in1 = fast_rsq(d1);
    u1x *= in1; u1y *= in1; u1z *= in1;
  } else {
    float au0 = fabsf(u0x), au1 = fabsf(u0y), au2 = fabsf(u0z);
    float e0 = 0.f, e1 = 0.f, e2 = 0.f;
    if (au0 <= au1 && au0 <= au2) e0 = 1.f; else if (au1 <= au2) e1 = 1.f; else e2 = 1.f;
    float d2 = e0*u0x + e1*u0y + e2*u0z;
    u1x = e0 - d2*u0x; u1y = e1 - d2*u0y; u1z = e2 - d2*u0z;
    float nn = fast_rsq(u1x*u1x + u1y*u1y + u1z*u1z);
    u1x *= nn; u1y *= nn; u1z *= nn;
  }
  float u2x = u0y*u1z - u0z*u1y;
  float u2y = u0z*u1x - u0x*u1z;
  float u2z = u0x*u1y - u0y*u1x;
  float cxv = b1*c2 - b2*c1;
  float cyv = b2*c0 - b0*c2;
  float czv = b0*c1 - b1*c0;
  float detV = a0*cxv + a1*cyv + a2*czv;
  float dd = (detV >= 0.f) ? 1.f : -1.f;
  float w2x = dd*u2x, w2y = dd*u2y, w2z = dd*u2z;
  r00=a0*u0x + b0*u1x + c0*w2x;  r01=a0*u0y + b0*u1y + c0*w2y;  r02=a0*u0z + b0*u1z + c0*w2z;
  r10=a1*u0x + b1*u1x + c1*w2x;  r11=a1*u0y + b1*u1y + c1*w2y;  r12=a1*u0z + b1*u1z + c1*w2z;
  r20=a2*u0x + b2*u1x + c2*w2x;  r21=a2*u0y + b2*u1y + c2*w2y;  r22=a2*u0z + b2*u1z + c2*w2z;
}

// ---------------- K1: raw-score mutual top-3, sparse exp, stats, candidates ---
__global__ __launch_bounds__(512, 4) void k1_kernel(
    const float* __restrict__ score, const float* __restrict__ refp,
    const float* __restrict__ srcp, const void* __restrict__ rmaskp,
    const void* __restrict__ smaskp, int* hdr, float* cand_vals, int* cand_idx,
    float* Hsr, int* pcount)
{
  __shared__ float tile[NN*NN];
  __shared__ float part[4][NN][3];
  __shared__ float c3sh[NN], r3sh[NN];
  __shared__ unsigned char smk[NN], rmk[NN];
  __shared__ float srcsh[NN*3];
  __shared__ float red[8][17];
  __shared__ int wsum[8];
  __shared__ int basesh;
  __shared__ int smode;
  const int b = blockIdx.x, t = threadIdx.x;
  const int r = t & 127, q = t >> 7;
  const int lane = t & 63, wv = t >> 6;

  if (t < 64){
    unsigned v = ((const unsigned*)rmaskp)[t];
    bool n01 = !(v == 0u || v == 1u);
    bool nf  = !(v == 0u || v == 0x3F800000u);
    unsigned long long b01 = __ballot(n01), bf = __ballot(nf);
    if (t == 0) smode = (b01 == 0ull) ? 0 : ((bf == 0ull) ? 2 : 1);
  }
  {
    const float4* s4 = (const float4*)(score + (size_t)b*NN*NN);
    float4* t4 = (float4*)tile;
    for (int j = t; j < NN*NN/4; j += 512) t4[j] = s4[j];
  }
  __syncthreads();

  if (t < NN){
    int mode = smode;
    smk[t] = read_mask(smaskp, b*NN + t, mode) ? 1 : 0;
    rmk[t] = read_mask(rmaskp, b*NN + t, mode) ? 1 : 0;
    srcsh[t*3+0] = srcp[(b*NN+t)*3+0];
    srcsh[t*3+1] = srcp[(b*NN+t)*3+1];
    srcsh[t*3+2] = srcp[(b*NN+t)*3+2];
  }
  {
    float a1=-1e30f, a2=-1e30f, a3=-1e30f;
    for (int i = 0; i < 32; i++){
      float v = tile[(q*32 + i)*NN + r];
      top3_update(v, a1, a2, a3);
    }
    part[q][r][0]=a1; part[q][r][1]=a2; part[q][r][2]=a3;
  }
  __syncthreads();
  if (t < NN){
    float m1=-1e30f, m2=-1e30f, m3=-1e30f;
#pragma unroll
    for (int qq = 0; qq < 4; qq++)
#pragma unroll
      for (int j = 0; j < 3; j++) top3_update(part[qq][t][j], m1, m2, m3);
    c3sh[t] = m3;
  }
  __syncthreads();
  {
    float a1=-1e30f, a2=-1e30f, a3=-1e30f;
    for (int i = 0; i < 32; i++){
      int c = q*32 + ((r + i) & 31);
      top3_update(tile[r*NN + c], a1, a2, a3);
    }
    part[q][r][0]=a1; part[q][r][1]=a2; part[q][r][2]=a3;
  }
  __syncthreads();
  if (t < NN){
    float m1=-1e30f, m2=-1e30f, m3=-1e30f;
#pragma unroll
    for (int qq = 0; qq < 4; qq++)
#pragma unroll
      for (int j = 0; j < 3; j++) top3_update(part[qq][t][j], m1, m2, m3);
    r3sh[t] = m3;
  }
  __syncthreads();

  float wr = 0.f, p0 = 0.f, p1 = 0.f, p2 = 0.f, cntf = 0.f;
  float kv[3]; int km[3]; int cnt = 0;
  const float r3 = r3sh[r];
  const bool rmv = rmk[r] != 0;
  const float rx = refp[(b*NN+r)*3+0], ry = refp[(b*NN+r)*3+1], rz = refp[(b*NN+r)*3+2];
  for (int i = 0; i < 32; i++){
    int c = q*32 + ((r + i) & 31);
    float v = tile[r*NN + c];
    if (rmv && smk[c] && v >= r3 && v >= c3sh[c]){
      float e = expf(v);
      if (e > 0.05f){
        cntf += 1.f; wr += e;
        p0 += e*srcsh[c*3+0]; p1 += e*srcsh[c*3+1]; p2 += e*srcsh[c*3+2];
        if (cnt < 3){ kv[cnt] = e; km[cnt] = c; cnt++; }
      }
    }
  }
  int x = cnt;
  for (int off2 = 1; off2 < 64; off2 <<= 1){ int y = __shfl_up(x, off2); if (lane >= off2) x += y; }
  if (lane == 63) wsum[wv] = x;
  __syncthreads();
  if (t == 0){
    int s2 = 0;
#pragma unroll
    for (int w = 0; w < 8; w++) s2 += wsum[w];
    basesh = atomicAdd(&hdr[0], s2);
  }
  __syncthreads();
  {
    int base = basesh + (x - cnt);
    for (int w = 0; w < wv; w++) base += wsum[w];
    for (int j = 0; j < cnt; j++){
      int pos = base + j;
      if (pos < CAND_CAP){ cand_vals[pos] = kv[j]; cand_idx[pos] = (b<<14)|(r<<7)|km[j]; }
    }
  }
  float qv[17];
  qv[0]=cntf; qv[1]=wr;
  qv[2]=wr*rx; qv[3]=wr*ry; qv[4]=wr*rz;
  qv[5]=p0; qv[6]=p1; qv[7]=p2;
  qv[8]=p0*rx;  qv[9]=p0*ry;  qv[10]=p0*rz;
  qv[11]=p1*rx; qv[12]=p1*ry; qv[13]=p1*rz;
  qv[14]=p2*rx; qv[15]=p2*ry; qv[16]=p2*rz;
#pragma unroll
  for (int k = 0; k < 17; k++){
    float v = qv[k];
    for (int off2 = 32; off2 > 0; off2 >>= 1) v += __shfl_down(v, off2);
    if (lane == 0) red[wv][k] = v;
  }
  __syncthreads();
  if (t == 0){
    float tot[17];
#pragma unroll
    for (int k = 0; k < 17; k++){
      float s2 = 0.f;
#pragma unroll
      for (int w = 0; w < 8; w++) s2 += red[w][k];
      tot[k] = s2;
    }
    float Wm = tot[1];
    float denom = Wm + 1e-5f;
    float idenom = 1.f / denom;
    float s = Wm * idenom;
    float rcv[3] = { tot[2]*idenom, tot[3]*idenom, tot[4]*idenom };
    float scv[3] = { tot[5]*idenom, tot[6]*idenom, tot[7]*idenom };
    float* o = &Hsr[b*15];
#pragma unroll
    for (int c = 0; c < 3; c++)
#pragma unroll
      for (int d = 0; d < 3; d++)
        o[c*3+d] = tot[8 + c*3 + d]*idenom - (2.f - s)*scv[c]*rcv[d];
    o[9]=scv[0]; o[10]=scv[1]; o[11]=scv[2];
    o[12]=rcv[0]; o[13]=rcv[1]; o[14]=rcv[2];
    pcount[b] = (int)(tot[0] + 0.5f);
  }
}

// ---------------- K3a: grid histogram of top-12 key bits (64 blocks) ----------
__global__ __launch_bounds__(256) void k3a_kernel(
    const int* hdr, const float* __restrict__ cand_vals, int* hist)
{
  __shared__ int lh[NBIN1];
  int t = threadIdx.x;
  int Nc = hdr[0]; if (Nc > CAND_CAP) Nc = CAND_CAP;
  for (int j = t; j < NBIN1; j += 256) lh[j] = 0;
  __syncthreads();
  for (int i = blockIdx.x*256 + t; i < Nc; i += gridDim.x*256)
    atomicAdd(&lh[__float_as_uint(cand_vals[i]) >> 20], 1);
  __syncthreads();
  for (int j = t; j < NBIN1; j += 256)
    if (lh[j]) atomicAdd(&hist[j], lh[j]);
}

// ---------------- K3c: parallel per-block boundary-find + grid partition ------
__global__ __launch_bounds__(256) void k3c_kernel(
    int* hdr, const int* __restrict__ hist,
    const float* __restrict__ cand_vals, const int* __restrict__ cand_idx,
    float* sel_vals, int* sel_idx, float* eq_vals, int* eq_idx)
{
  __shared__ int wtot[4];
  __shared__ int sb[2];
  const int t = threadIdx.x, lane = t & 63, wv = t >> 6;
  int Nc = hdr[0]; if (Nc > CAND_CAP) Nc = CAND_CAP;
  // every block derives (bin1, need) from hist in parallel (hist final at dispatch)
  if (Nc <= LIMIT){
    if (t == 0){ sb[0] = -1; sb[1] = 0; if (blockIdx.x == 0){ hdr[4] = -1; hdr[5] = 0; } }
    __syncthreads();
  } else {
    const int chunkIdx = 255 - t;          // thread 0 owns the TOP chunk
    int csum = 0;
    for (int j = 0; j < 16; j++) csum += hist[chunkIdx*16 + j];
    int incl = csum;
    for (int off = 1; off < 64; off <<= 1){ int y = __shfl_up(incl, off); if (lane >= off) incl += y; }
    if (lane == 63) wtot[wv] = incl;
    __syncthreads();
    int wbase = 0;
    for (int w = 0; w < wv; w++) wbase += wtot[w];
    int P = wbase + incl;                  // suffix-sum down to this chunk
    int P_prev = P - csum;
    if (P_prev < LIMIT && P >= LIMIT){     // unique owner thread
      int cum = P_prev, bin1 = chunkIdx*16, need = 0;
      for (int b2 = chunkIdx*16 + 15; b2 >= chunkIdx*16; b2--){
        int h = hist[b2];
        if (cum + h >= LIMIT){ bin1 = b2; need = LIMIT - cum; break; }
        cum += h;
      }
      sb[0] = bin1; sb[1] = need;
      if (blockIdx.x == 0){ hdr[4] = bin1; hdr[5] = need; }
    }
    __syncthreads();
  }
  int bin1 = sb[0];
  for (int i = blockIdx.x*256 + t; i < Nc; i += gridDim.x*256){
    float v = cand_vals[i];
    if (bin1 < 0){
      int p = atomicAdd(&hdr[2], 1);
      if (p < LIMIT){ sel_vals[p] = v; sel_idx[p] = cand_idx[i]; }
      continue;
    }
    int bin = (int)(__float_as_uint(v) >> 20);
    if (bin > bin1){
      int p = atomicAdd(&hdr[2], 1);
      if (p < LIMIT){ sel_vals[p] = v; sel_idx[p] = cand_idx[i]; }
    } else if (bin == bin1){
      int q = atomicAdd(&hdr[1], 1);
      if (q < EQCAP){ eq_vals[q] = v; eq_idx[q] = cand_idx[i]; }
    }
  }
}

// ---------------- K3d: refine boundary bin + zero-fill + gather ---------------
__global__ __launch_bounds__(1024) void k3d_kernel(
    const int* hdr, const float* __restrict__ eq_vals, const int* __restrict__ eq_idx,
    float* sel_vals, int* sel_idx,
    const float* __restrict__ refp, const float* __restrict__ srcp,
    float* sel_ref, float* sel_src)
{
  __shared__ int hist[2048];
  __shared__ int eqsh[2048];
  __shared__ int wtot[16];
  __shared__ int bpair[2];
  __shared__ int sh[2];
  const int t = threadIdx.x, lane = t & 63, wv = t >> 6;
  const int bin1 = hdr[4];
  int nAbove = hdr[2]; if (nAbove > LIMIT) nAbove = LIMIT;

  // constant-stride boundary-find: thread t owns reversed bins 2047-2t, 2046-2t
  auto find_boundary = [&](int need){
    int i0 = 2047 - 2*t, i1 = 2046 - 2*t;
    int g0 = hist[i0], g1 = hist[i1];
    int local = g0 + g1;
    int incl = local;
    for (int off = 1; off < 64; off <<= 1){ int y = __shfl_up(incl, off); if (lane >= off) incl += y; }
    if (lane == 63) wtot[wv] = incl;
    __syncthreads();
    int wbase = 0;
    for (int w = 0; w < wv; w++) wbase += wtot[w];
    int P_prev = wbase + incl - local;
    int P0 = P_prev + g0;
    if (P0 >= need && P_prev < need){ bpair[0] = i0; bpair[1] = need - P_prev; }
    int P1 = P0 + g1;
    if (P1 >= need && P0 < need){ bpair[0] = i1; bpair[1] = need - P0; }
    __syncthreads();
  };

  bool done = false;
  if (bin1 < 0){
    for (int i = t; i < LIMIT; i += 1024)
      if (i >= nAbove){ sel_vals[i] = 0.f; sel_idx[i] = 0; }
    done = true;
  }
  int neq = 0, need = 0;
  if (!done){
    neq = hdr[1]; if (neq > EQCAP) neq = EQCAP;
    need = hdr[5];
    if (need >= neq){
      for (int i = t; i < neq; i += 1024){ sel_vals[nAbove+i] = eq_vals[i]; sel_idx[nAbove+i] = eq_idx[i]; }
      for (int i = t; i < LIMIT; i += 1024)
        if (i >= nAbove + neq){ sel_vals[i] = 0.f; sel_idx[i] = 0; }
      done = true;
    }
  }
  if (!done){
    // pass A: bits 19..9 (2048 bins)
    for (int i = t; i < 2048; i += 1024) hist[i] = 0;
    __syncthreads();
    for (int i = t; i < neq; i += 1024)
      atomicAdd(&hist[(__float_as_uint(eq_vals[i]) >> 9) & 0x7FF], 1);
    __syncthreads();
    find_boundary(need);
    int binA = bpair[0], need2 = bpair[1];
    __syncthreads();
    // pass B: bits 8..0 (512 bins, same array)
    for (int i = t; i < 2048; i += 1024) hist[i] = 0;
    __syncthreads();
    for (int i = t; i < neq; i += 1024){
      unsigned k = __float_as_uint(eq_vals[i]);
      if ((int)((k >> 9) & 0x7FF) == binA) atomicAdd(&hist[k & 0x1FF], 1);
    }
    __syncthreads();
    find_boundary(need2);
    unsigned Tlow = (((unsigned)binA) << 9) | (unsigned)bpair[0];
    unsigned Tkey = (((unsigned)bin1) << 20) | Tlow;
    if (t == 0){ sh[0] = 0; sh[1] = 0; }
    __syncthreads();
    for (int i = t; i < neq; i += 1024){
      unsigned k = __float_as_uint(eq_vals[i]);
      unsigned k20 = k & 0xFFFFF;
      if (k20 > Tlow){
        int p = atomicAdd(&sh[0], 1);
        sel_vals[nAbove + p] = eq_vals[i]; sel_idx[nAbove + p] = eq_idx[i];
      } else if (k20 == Tlow){
        int q = atomicAdd(&sh[1], 1);
        if (q < 2048) eqsh[q] = eq_idx[i];
      }
    }
    __syncthreads();
    if (t == 0){
      int na2 = sh[0];
      int ne2 = sh[1]; if (ne2 > 2048) ne2 = 2048;
      int take = need - na2; if (take > ne2) take = ne2; if (take < 0) take = 0;
      if (nAbove + na2 + take > LIMIT) take = LIMIT - nAbove - na2;
      // tie-break: smallest flat index first (matches jax.lax.top_k)
      for (int j = 0; j < take; j++){
        int mi = j;
        for (int l = j+1; l < ne2; l++) if (eqsh[l] < eqsh[mi]) mi = l;
        int tmp = eqsh[j]; eqsh[j] = eqsh[mi]; eqsh[mi] = tmp;
        sel_vals[nAbove + na2 + j] = __uint_as_float(Tkey);
        sel_idx[nAbove + na2 + j] = eqsh[j];
      }
      for (int j = nAbove + na2 + take; j < LIMIT; j++){ sel_vals[j] = 0.f; sel_idx[j] = 0; }
    }
  }
  __syncthreads();   // own-block global writes ordered; gather points
  for (int p = t; p < LIMIT; p += 1024){
    int idx = sel_idx[p];
    int b = idx >> 14, rr = (idx >> 7) & 127, ss = idx & 127;
#pragma unroll
    for (int c = 0; c < 3; c++){
      sel_ref[p*3+c] = refp[(b*NN+rr)*3+c];
      sel_src[p*3+c] = srcp[(b*NN+ss)*3+c];
    }
  }
}

// ---------------- K45: per-block Kabsch + inlier counts + last-block refine ---
__global__ __launch_bounds__(256) void k45_kernel(
    const float* __restrict__ Hsr, float* __restrict__ localT,
    const float* __restrict__ sel_vals, const float* __restrict__ sel_ref,
    const float* __restrict__ sel_src, const int* __restrict__ pcount,
    int* counts, int* hdr, float* out)
{
  __shared__ float Tsh[12];
  __shared__ int ired[4];
  __shared__ int lastsh;
  __shared__ double dred[4][16];
  __shared__ long long lred[4];
  __shared__ float RT[12];
  __shared__ int sbest;
  const int b = blockIdx.x, t = threadIdx.x, lane = t & 63, wv = t >> 6;

  if (t == 0){
    const float* o = &Hsr[b*15];
    float r00,r01,r02,r10,r11,r12,r20,r21,r22;
    kabsch9(o[0],o[1],o[2], o[3],o[4],o[5], o[6],o[7],o[8],
            r00,r01,r02,r10,r11,r12,r20,r21,r22);
    Tsh[0]=r00; Tsh[1]=r01; Tsh[2]=r02;
    Tsh[3]=r10; Tsh[4]=r11; Tsh[5]=r12;
    Tsh[6]=r20; Tsh[7]=r21; Tsh[8]=r22;
    Tsh[9]  = o[12] - (r00*o[9] + r01*o[10] + r02*o[11]);
    Tsh[10] = o[13] - (r10*o[9] + r11*o[10] + r12*o[11]);
    Tsh[11] = o[14] - (r20*o[9] + r21*o[10] + r22*o[11]);
  }
  __syncthreads();
  if (t < 12) localT[b*12 + t] = Tsh[t];

  {
    float R00=Tsh[0],R01=Tsh[1],R02=Tsh[2],R10=Tsh[3],R11=Tsh[4],R12=Tsh[5];
    float R20=Tsh[6],R21=Tsh[7],R22=Tsh[8];
    float tx=Tsh[9], ty=Tsh[10], tz=Tsh[11];
    int c = 0;
    for (int p = t; p < LIMIT; p += 256){
      float v = sel_vals[p];
      if (!(v > 0.f)) continue;
      float sx=sel_src[p*3], sy=sel_src[p*3+1], sz=sel_src[p*3+2];
      float rx=sel_ref[p*3], ry=sel_ref[p*3+1], rz=sel_ref[p*3+2];
      float ax = R00*sx + R01*sy + R02*sz + tx;
      float ay = R10*sx + R11*sy + R12*sz + ty;
      float az = R20*sx + R21*sy + R22*sz + tz;
      float dx = rx-ax, dy = ry-ay, dz = rz-az;
      if (sqrtf(dx*dx + dy*dy + dz*dz) < 0.1f) c++;
    }
    for (int off2 = 32; off2 > 0; off2 >>= 1) c += __shfl_down(c, off2);
    if (lane == 0) ired[wv] = c;
    __syncthreads();
    if (t == 0){
      counts[b] = (pcount[b] >= 3) ? (ired[0]+ired[1]+ired[2]+ired[3]) : -1;
      __threadfence();
      int d = atomicAdd(&hdr[6], 1);
      lastsh = (d == BB - 1) ? 1 : 0;
    }
    __syncthreads();
    if (!lastsh) return;
    __threadfence();
  }

  {
    long long key = (long long)0x8000000000000000LL;
    for (int bb = t; bb < BB; bb += 256){
      long long kk = ((long long)(counts[bb] + 2) << 32) | (long long)(511 - bb);
      if (kk > key) key = kk;
    }
    for (int off2 = 32; off2 > 0; off2 >>= 1){ long long o = __shfl_down(key, off2); if (o > key) key = o; }
    if (lane == 0) lred[wv] = key;
    __syncthreads();
    if (t == 0){
      long long m = lred[0];
#pragma unroll
      for (int w = 1; w < 4; w++) if (lred[w] > m) m = lred[w];
      sbest = 511 - (int)(m & 0xFFFFFFFFLL);
    }
    __syncthreads();
    if (t < 12) RT[t] = localT[sbest*12 + t];
    __syncthreads();

    for (int iter = 0; iter < 5; iter++){
      float R00=RT[0],R01=RT[1],R02=RT[2];
      float R10=RT[3],R11=RT[4],R12=RT[5];
      float R20=RT[6],R21=RT[7],R22=RT[8];
      float tx=RT[9], ty=RT[10], tz=RT[11];
      double a[16];
#pragma unroll
      for (int k = 0; k < 16; k++) a[k] = 0.0;
      for (int p = t; p < LIMIT; p += 256){
        float v = sel_vals[p];
        if (!(v > 0.f)) continue;
        float sx=sel_src[p*3], sy=sel_src[p*3+1], sz=sel_src[p*3+2];
        float rx=sel_ref[p*3], ry=sel_ref[p*3+1], rz=sel_ref[p*3+2];
        float ax = R00*sx + R01*sy + R02*sz + tx;
        float ay = R10*sx + R11*sy + R12*sz + ty;
        float az = R20*sx + R21*sy + R22*sz + tz;
        float dx = rx-ax, dy = ry-ay, dz = rz-az;
        if (sqrtf(dx*dx + dy*dy + dz*dz) < 0.1f){
          double w = (double)v;
          a[0] += w;
          a[1] += w*sx; a[2] += w*sy; a[3] += w*sz;
          a[4] += w*rx; a[5] += w*ry; a[6] += w*rz;
          a[7]  += w*sx*rx; a[8]  += w*sx*ry; a[9]  += w*sx*rz;
          a[10] += w*sy*rx; a[11] += w*sy*ry; a[12] += w*sy*rz;
          a[13] += w*sz*rx; a[14] += w*sz*ry; a[15] += w*sz*rz;
        }
      }
#pragma unroll
      for (int k = 0; k < 16; k++){
        double v = a[k];
        for (int off2 = 32; off2 > 0; off2 >>= 1) v += __shfl_down(v, off2);
        if (lane == 0) dred[wv][k] = v;
      }
      __syncthreads();
      if (t == 0){
        double tot[16];
#pragma unroll
        for (int k = 0; k < 16; k++) tot[k] = dred[0][k]+dred[1][k]+dred[2][k]+dred[3][k];
        double W = tot[0], denom = W + 1e-5;
        double inv = 1.0 / denom;
        double s = W * inv;
        double scv[3] = { tot[1]*inv, tot[2]*inv, tot[3]*inv };
        double rcv[3] = { tot[4]*inv, tot[5]*inv, tot[6]*inv };
        float h00 = (float)(tot[7]*inv  - (2.0 - s)*scv[0]*rcv[0]);
        float h01 = (float)(tot[8]*inv  - (2.0 - s)*scv[0]*rcv[1]);
        float h02 = (float)(tot[9]*inv  - (2.0 - s)*scv[0]*rcv[2]);
        float h10 = (float)(tot[10]*inv - (2.0 - s)*scv[1]*rcv[0]);
        float h11 = (float)(tot[11]*inv - (2.0 - s)*scv[1]*rcv[1]);
        float h12 = (float)(tot[12]*inv - (2.0 - s)*scv[1]*rcv[2]);
        float h20 = (float)(tot[13]*inv - (2.0 - s)*scv[2]*rcv[0]);
        float h21 = (float)(tot[14]*inv - (2.0 - s)*scv[2]*rcv[1]);
        float h22 = (float)(tot[15]*inv - (2.0 - s)*scv[2]*rcv[2]);
        float r00,r01,r02,r10,r11,r12,r20,r21,r22;
        kabsch9(h00,h01,h02,h10,h11,h12,h20,h21,h22,
                r00,r01,r02,r10,r11,r12,r20,r21,r22);
        RT[0]=r00; RT[1]=r01; RT[2]=r02;
        RT[3]=r10; RT[4]=r11; RT[5]=r12;
        RT[6]=r20; RT[7]=r21; RT[8]=r22;
        RT[9]  = (float)(rcv[0] - ((double)r00*scv[0] + (double)r01*scv[1] + (double)r02*scv[2]));
        RT[10] = (float)(rcv[1] - ((double)r10*scv[0] + (double)r11*scv[1] + (double)r12*scv[2]));
        RT[11] = (float)(rcv[2] - ((double)r20*scv[0] + (double)r21*scv[1] + (double)r22*scv[2]));
      }
      __syncthreads();
    }
    if (t == 0){
      out[0]=RT[0];  out[1]=RT[1];  out[2]=RT[2];  out[3]=RT[9];
      out[4]=RT[3];  out[5]=RT[4];  out[6]=RT[5];  out[7]=RT[10];
      out[8]=RT[6];  out[9]=RT[7];  out[10]=RT[8]; out[11]=RT[11];
      out[12]=0.f; out[13]=0.f; out[14]=0.f; out[15]=1.f;
    }
  }
}

// ---------------- host launcher -----------------------------------------------
extern "C" void kernel_launch(void* const* d_in, const int* in_sizes, int n_in,
                              void* d_out, int out_size, void* d_ws, size_t ws_size,
                              hipStream_t stream){
  const float* score = (const float*)d_in[0];
  const float* refp  = (const float*)d_in[1];
  const float* srcp  = (const float*)d_in[2];
  const void*  rmask = d_in[3];
  const void*  smask = d_in[4];

  char* ws = (char*)d_ws;
  size_t off = 0;
  int* hdr = (int*)(ws + off);            off += 256;
  int* hist = (int*)(ws + off);           off += (size_t)NBIN1*4;
  float* cand_vals = (float*)(ws + off);  off += (size_t)CAND_CAP*4;
  int* cand_idx = (int*)(ws + off);       off += (size_t)CAND_CAP*4;
  float* eq_vals = (float*)(ws + off);    off += (size_t)EQCAP*4;
  int* eq_idx = (int*)(ws + off);         off += (size_t)EQCAP*4;
  float* Hsr = (float*)(ws + off);        off += (size_t)BB*15*4;
  int* pcount = (int*)(ws + off);         off += (size_t)BB*4;
  float* localT = (float*)(ws + off);     off += (size_t)BB*12*4;
  float* sel_vals = (float*)(ws + off);   off += (size_t)LIMIT*4;
  int* sel_idx = (int*)(ws + off);        off += (size_t)LIMIT*4;
  float* sel_ref = (float*)(ws + off);    off += (size_t)LIMIT*3*4;
  float* sel_src = (float*)(ws + off);    off += (size_t)LIMIT*3*4;
  int* counts = (int*)(ws + off);         off += (size_t)BB*4;

  hipMemsetAsync(ws, 0, 256 + (size_t)NBIN1*4, stream);
  hipLaunchKernelGGL(k1_kernel, dim3(BB), dim3(512), 0, stream,
                     score, refp, srcp, rmask, smask, hdr, cand_vals, cand_idx, Hsr, pcount);
  hipLaunchKernelGGL(k3a_kernel, dim3(64), dim3(256), 0, stream, hdr, cand_vals, hist);
  hipLaunchKernelGGL(k3c_kernel, dim3(64), dim3(256), 0, stream,
                     hdr, hist, cand_vals, cand_idx, sel_vals, sel_idx, eq_vals, eq_idx);
  hipLaunchKernelGGL(k3d_kernel, dim3(1), dim3(1024), 0, stream,
                     hdr, eq_vals, eq_idx, sel_vals, sel_idx, refp, srcp, sel_ref, sel_src);
  hipLaunchKernelGGL(k45_kernel, dim3(BB), dim3(256), 0, stream,
                     Hsr, localT, sel_vals, sel_ref, sel_src, pcount, counts, hdr, (float*)d_out);
}